// Round 2
// baseline (4493.810 us; speedup 1.0000x reference)
//
#include <hip/hip_runtime.h>

#define BB 4
#define NN 4096
#define KK 16

typedef unsigned short u16;
typedef unsigned int   u32;
typedef unsigned long long u64;

__device__ __forceinline__ float b2f(u16 x){ return __uint_as_float(((u32)x) << 16); }
__device__ __forceinline__ u16 f2b(float f){
    u32 u = __float_as_uint(f);
    u32 r = (u + 0x7FFFu + ((u >> 16) & 1u)) >> 16;   // RNE
    return (u16)r;
}
// order-preserving f32 -> u32 map (for atomicMax-based float max)
__device__ __forceinline__ u32 fmap(float f){
    u32 u = __float_as_uint(f);
    return (u & 0x80000000u) ? ~u : (u | 0x80000000u);
}
__device__ __forceinline__ float funmap(u32 u){
    u32 v = (u & 0x80000000u) ? (u ^ 0x80000000u) : ~u;
    return __uint_as_float(v);
}

// ---------------- input normalization (runtime dtype detect: f32 vs bf16) ----
#define N_ARR 27
__device__ const int ASZ[N_ARR] = {
    49152, 384, 64, 64, 64, 8192, 128, 128, 128, 32768, 256,
    66304, 256, 256, 256, 131072, 512, 512, 512, 524288, 1024,
    655360, 512, 131072, 256, 4096, 16 };
__device__ const int AOFF[N_ARR] = {
    0, 49152, 49536, 49600, 49664, 49728, 57920, 58048, 58176, 58304, 91072,
    91328, 157632, 157888, 158144, 158400, 289472, 289984, 290496, 291008, 815296,
    816320, 1471680, 1472192, 1603264, 1603520, 1607616 };

struct Ptrs { const void* p[N_ARR]; };

// f32 element offsets within conv region
#define O_POS 0
#define O_CW1 49152
#define O_CB1 49536
#define O_CG1 49600
#define O_CS1 49664
#define O_CW2 49728
#define O_CB2 57920
#define O_CG2 58048
#define O_CS2 58176
#define O_CW3 58304
#define O_CB3 91072
#define O_SW1 91328
#define O_SB1 157632
#define O_SG1 157888
#define O_SS1 158144
#define O_SW2 158400
#define O_SB2 289472
#define O_SG2 289984
#define O_SS2 290496
#define O_SW3 291008
#define O_SB3 815296
#define O_PW1 816320
#define O_PB1 1471680
#define O_PW2 1472192
#define O_PB2 1603264
#define O_PW3 1603520
#define O_PB3 1607616

__global__ void detect_kernel(const u16* __restrict__ pos_u16, u32* __restrict__ flag){
    // Even-index u16s: if data is f32, these are low mantissa halves (uniform
    // exponent field). If bf16, they are N(0,1) bf16 values (exponent ~[0x68,0x82]).
    __shared__ int cnt;
    if (threadIdx.x == 0) cnt = 0;
    __syncthreads();
    int c = 0;
    #pragma unroll
    for (int s = 0; s < 4; ++s){
        u16 u = pos_u16[2*(threadIdx.x*4 + s)];
        int e = (u >> 7) & 0xFF;
        c += (e >= 0x68 && e <= 0x82) ? 1 : 0;
    }
    atomicAdd(&cnt, c);
    __syncthreads();
    if (threadIdx.x == 0) *flag = (cnt >= 512) ? 1u : 0u;   // 1 = bf16 inputs
}

__global__ __launch_bounds__(256) void convert_kernel(Ptrs pt, const u32* __restrict__ flagp,
                                                      float* __restrict__ dst){
    const bool isbf = (*flagp != 0);
    const int T = gridDim.x * 256;
    const int g = blockIdx.x * 256 + threadIdx.x;
    #pragma unroll
    for (int a = 0; a < N_ARR; ++a){
        const int sz = ASZ[a], off = AOFF[a];
        if (isbf){
            const u16* s = (const u16*)pt.p[a];
            for (int i = g; i < sz; i += T) dst[off + i] = b2f(s[i]);
        } else {
            const float* s = (const float*)pt.p[a];
            for (int i = g; i < sz; i += T) dst[off + i] = s[i];
        }
    }
}

// ---------------------------------------------------------------- kNN
__global__ __launch_bounds__(256) void knn_kernel(const float* __restrict__ conv,
                                                  int* __restrict__ knn_out){
    __shared__ float sx[NN], sy[NN], sz[NN];
    const float* posf = conv + O_POS;
    const int b  = blockIdx.x >> 10;
    const int i0 = (blockIdx.x & 1023) << 2;
    const int tid = threadIdx.x;
    for (int t = tid; t < NN; t += 256){
        const float* p = posf + ((size_t)(b*NN + t))*3;
        sx[t] = p[0]; sy[t] = p[1]; sz[t] = p[2];
    }
    __syncthreads();
    const int lane = tid & 63;
    const int i = i0 + (tid >> 6);
    const float pix = sx[i], piy = sy[i], piz = sz[i];

    float d[KK]; int id[KK];
    #pragma unroll
    for (int t = 0; t < KK; ++t){
        int j = lane + (t << 6);
        float dx = pix - sx[j], dy = piy - sy[j], dz = piz - sz[j];
        d[t] = __fadd_rn(__fadd_rn(__fmul_rn(dx,dx), __fmul_rn(dy,dy)), __fmul_rn(dz,dz));
        id[t] = j;
    }
    float dmax = d[0]; int amax = 0;
    #pragma unroll
    for (int p = 1; p < KK; ++p){ bool c = d[p] > dmax; dmax = c ? d[p] : dmax; amax = c ? p : amax; }

    for (int t = KK; t < 64; ++t){
        int j = lane + (t << 6);
        float dx = pix - sx[j], dy = piy - sy[j], dz = piz - sz[j];
        float d2 = __fadd_rn(__fadd_rn(__fmul_rn(dx,dx), __fmul_rn(dy,dy)), __fmul_rn(dz,dz));
        if (d2 < dmax){           // strict <: earlier index wins ties (matches stable top_k)
            #pragma unroll
            for (int p = 0; p < KK; ++p){ bool c = (p == amax); d[p] = c ? d2 : d[p]; id[p] = c ? j : id[p]; }
            dmax = d[0]; amax = 0;
            #pragma unroll
            for (int p = 1; p < KK; ++p){ bool c = d[p] > dmax; dmax = c ? d[p] : dmax; amax = c ? p : amax; }
        }
    }
    u64 key[KK];
    #pragma unroll
    for (int p = 0; p < KK; ++p) key[p] = (((u64)__float_as_uint(d[p])) << 32) | (u32)id[p];
    int* outp = knn_out + ((size_t)(b*NN + i))*KK;
    for (int r = 0; r < KK; ++r){
        u64 m = key[0];
        #pragma unroll
        for (int p = 1; p < KK; ++p) m = key[p] < m ? key[p] : m;
        #pragma unroll
        for (int off = 32; off > 0; off >>= 1){
            u64 o = __shfl_xor(m, off);
            m = o < m ? o : m;
        }
        if (lane == 0) outp[r] = (int)(u32)(m & 0xFFFFFFFFu);
        #pragma unroll
        for (int p = 0; p < KK; ++p) if (key[p] == m) key[p] = ~0ull;
    }
}

// ---------------------------------------------------------------- edge MLP + scatter-max
__global__ __launch_bounds__(256) void edge_kernel(
    const float* __restrict__ conv, const int* __restrict__ knn,
    u32* __restrict__ xmap)
{
    __shared__ float in6[6][64];
    __shared__ int   jt[64];
    __shared__ __align__(16) u16 h1s[64][64];    // [ch][edge] bf16
    __shared__ __align__(16) u16 h2s[128][64];
    __shared__ float sc1[64], sh1[64], sc2[128], sh2[128];
    const float* posf = conv + O_POS;
    const float* cw1 = conv + O_CW1; const float* cb1 = conv + O_CB1;
    const float* cg1 = conv + O_CG1; const float* cs1 = conv + O_CS1;
    const float* cw2 = conv + O_CW2; const float* cb2 = conv + O_CB2;
    const float* cg2 = conv + O_CG2; const float* cs2 = conv + O_CS2;
    const float* cw3 = conv + O_CW3; const float* cb3 = conv + O_CB3;

    const int tid = threadIdx.x;
    const int e0g = blockIdx.x << 6;
    const int b   = e0g >> 16;                    // N*K = 65536 edges per batch

    if (tid < 64){
        int e = e0g + tid;
        int i = (e >> 4) & (NN - 1);
        int j = knn[e];
        jt[tid] = j;
        const float* pi = posf + ((size_t)(b*NN + i))*3;
        const float* pj = posf + ((size_t)(b*NN + j))*3;
        float ax=pi[0], ay=pi[1], az=pi[2];
        float bx=pj[0], by=pj[1], bz=pj[2];
        in6[0][tid]=ax; in6[1][tid]=ay; in6[2][tid]=az;
        in6[3][tid]=ax-bx; in6[4][tid]=ay-by; in6[5][tid]=az-bz;
        float g1 = cg1[tid]; sc1[tid]=g1; sh1[tid]=cb1[tid]*g1 + cs1[tid];
    }
    if (tid < 128){ float g2=cg2[tid]; sc2[tid]=g2; sh2[tid]=cb2[tid]*g2 + cs2[tid]; }
    __syncthreads();

    { // layer 1: wave w -> channels w*16..+15, lane = edge
        const int lane = tid & 63, w = tid >> 6;
        float a0=in6[0][lane], a1=in6[1][lane], a2=in6[2][lane],
              a3=in6[3][lane], a4=in6[4][lane], a5=in6[5][lane];
        #pragma unroll
        for (int ci = 0; ci < 16; ++ci){
            int c = (w << 4) + ci;
            float acc = a0*cw1[c]     + a1*cw1[64+c]  + a2*cw1[128+c]
                      + a3*cw1[192+c] + a4*cw1[256+c] + a5*cw1[320+c];
            acc = fmaxf(acc*sc1[c] + sh1[c], 0.f);
            h1s[c][lane] = f2b(acc);
        }
    }
    __syncthreads();

    { // layer 2: thread tile 4 edges x 8 channels
        const int e0 = (tid & 15) << 2, c0 = (tid >> 4) << 3;
        float acc[8][4];
        #pragma unroll
        for (int cc=0;cc<8;++cc){
            #pragma unroll
            for (int ee=0;ee<4;++ee) acc[cc][ee]=0.f;
        }
        for (int r = 0; r < 64; ++r){
            ushort4 av = *(const ushort4*)&h1s[r][e0];
            float a[4] = { b2f(av.x), b2f(av.y), b2f(av.z), b2f(av.w) };
            float4 wa = *(const float4*)(cw2 + r*128 + c0);
            float4 wb = *(const float4*)(cw2 + r*128 + c0 + 4);
            float w[8] = {wa.x,wa.y,wa.z,wa.w, wb.x,wb.y,wb.z,wb.w};
            #pragma unroll
            for (int cc=0;cc<8;++cc){
                #pragma unroll
                for (int ee=0;ee<4;++ee) acc[cc][ee] += w[cc]*a[ee];
            }
        }
        #pragma unroll
        for (int cc=0;cc<8;++cc){
            int c = c0 + cc;
            float s = sc2[c], h = sh2[c];
            ushort4 o;
            o.x = f2b(fmaxf(acc[cc][0]*s+h,0.f));
            o.y = f2b(fmaxf(acc[cc][1]*s+h,0.f));
            o.z = f2b(fmaxf(acc[cc][2]*s+h,0.f));
            o.w = f2b(fmaxf(acc[cc][3]*s+h,0.f));
            *(ushort4*)&h2s[c][e0] = o;
        }
    }
    __syncthreads();

    { // layer 3 (+ bias) + scatter-max: thread tile 4 edges x 16 channels
        const int e0 = (tid & 15) << 2, c0 = (tid >> 4) << 4;
        float acc[16][4];
        #pragma unroll
        for (int cc=0;cc<16;++cc){
            #pragma unroll
            for (int ee=0;ee<4;++ee) acc[cc][ee]=0.f;
        }
        for (int r = 0; r < 128; ++r){
            ushort4 av = *(const ushort4*)&h2s[r][e0];
            float a[4] = { b2f(av.x), b2f(av.y), b2f(av.z), b2f(av.w) };
            float4 w0 = *(const float4*)(cw3 + r*256 + c0);
            float4 w1 = *(const float4*)(cw3 + r*256 + c0 + 4);
            float4 w2 = *(const float4*)(cw3 + r*256 + c0 + 8);
            float4 w3 = *(const float4*)(cw3 + r*256 + c0 + 12);
            float w[16] = {w0.x,w0.y,w0.z,w0.w, w1.x,w1.y,w1.z,w1.w,
                           w2.x,w2.y,w2.z,w2.w, w3.x,w3.y,w3.z,w3.w};
            #pragma unroll
            for (int cc=0;cc<16;++cc){
                #pragma unroll
                for (int ee=0;ee<4;++ee) acc[cc][ee] += w[cc]*a[ee];
            }
        }
        u32 base0 = ((u32)(b*NN + jt[e0+0])) << 8;
        u32 base1 = ((u32)(b*NN + jt[e0+1])) << 8;
        u32 base2 = ((u32)(b*NN + jt[e0+2])) << 8;
        u32 base3 = ((u32)(b*NN + jt[e0+3])) << 8;
        #pragma unroll
        for (int cc=0;cc<16;++cc){
            int c = c0 + cc;
            float bias = cb3[c];
            atomicMax(xmap + base0 + c, fmap(acc[cc][0] + bias));
            atomicMax(xmap + base1 + c, fmap(acc[cc][1] + bias));
            atomicMax(xmap + base2 + c, fmap(acc[cc][2] + bias));
            atomicMax(xmap + base3 + c, fmap(acc[cc][3] + bias));
        }
    }
}

// ---------------------------------------------------------------- GlobalSA MLP + scene max
#define SAS 36   // padded point-stride
__global__ __launch_bounds__(256) void sa_kernel(
    const float* __restrict__ conv, const u32* __restrict__ xmap,
    u32* __restrict__ scene_map)
{
    __shared__ __align__(16) char smem[61440];
    u16* h1p = (u16*)smem;                 // [256][36] bf16  (18432 B)
    u16* a0p = (u16*)(smem + 18432);       // [259][36] bf16  (phase A)
    u16* h2p = (u16*)(smem + 18432);       // [512][36] bf16  (reuses a0 region)
    float* sc1 = (float*)(smem + 55296);   // 256
    float* sh1 = sc1 + 256;
    float* sc2 = sh1 + 256;                // 512
    float* sh2 = sc2 + 512;

    const float* posf = conv + O_POS;
    const float* sw1 = conv + O_SW1; const float* sb1 = conv + O_SB1;
    const float* sg1 = conv + O_SG1; const float* ss1 = conv + O_SS1;
    const float* sw2 = conv + O_SW2; const float* sb2 = conv + O_SB2;
    const float* sg2 = conv + O_SG2; const float* ss2 = conv + O_SS2;
    const float* sw3 = conv + O_SW3; const float* sb3 = conv + O_SB3;

    const int tid = threadIdx.x;
    const int b  = blockIdx.x >> 7;
    const int n0 = (blockIdx.x & 127) << 5;     // 32 points per block

    for (int u = tid; u < 32*256; u += 256){
        int p = u >> 8, c = u & 255;
        float f = funmap(xmap[(((u32)(b*NN + n0 + p)) << 8) + c]);
        a0p[c*SAS + p] = f2b(f);
    }
    if (tid < 96){
        int p = tid & 31, cc = tid >> 5;
        a0p[(256+cc)*SAS + p] = f2b(posf[((size_t)(b*NN + n0 + p))*3 + cc]);
    }
    if (tid < 256){ float g = sg1[tid]; sc1[tid]=g; sh1[tid]=sb1[tid]*g + ss1[tid]; }
    for (int u = tid; u < 512; u += 256){ float g=sg2[u]; sc2[u]=g; sh2[u]=sb2[u]*g + ss2[u]; }
    __syncthreads();

    { // s1: 259 -> 256 ; thread tile 4 pts x 8 ch
        const int p0 = (tid & 7) << 2, c0 = (tid >> 3) << 3;
        float acc[8][4];
        #pragma unroll
        for (int cc=0;cc<8;++cc){
            #pragma unroll
            for (int ee=0;ee<4;++ee) acc[cc][ee]=0.f;
        }
        for (int r = 0; r < 259; ++r){
            ushort4 av = *(const ushort4*)&a0p[r*SAS + p0];
            float a[4] = { b2f(av.x), b2f(av.y), b2f(av.z), b2f(av.w) };
            float4 wa = *(const float4*)(sw1 + r*256 + c0);
            float4 wb = *(const float4*)(sw1 + r*256 + c0 + 4);
            float w[8] = {wa.x,wa.y,wa.z,wa.w, wb.x,wb.y,wb.z,wb.w};
            #pragma unroll
            for (int cc=0;cc<8;++cc){
                #pragma unroll
                for (int ee=0;ee<4;++ee) acc[cc][ee] += w[cc]*a[ee];
            }
        }
        #pragma unroll
        for (int cc=0;cc<8;++cc){
            int c = c0 + cc;
            float s = sc1[c], h = sh1[c];
            ushort4 o;
            o.x=f2b(fmaxf(acc[cc][0]*s+h,0.f)); o.y=f2b(fmaxf(acc[cc][1]*s+h,0.f));
            o.z=f2b(fmaxf(acc[cc][2]*s+h,0.f)); o.w=f2b(fmaxf(acc[cc][3]*s+h,0.f));
            *(ushort4*)&h1p[c*SAS + p0] = o;
        }
    }
    __syncthreads();

    { // s2: 256 -> 512 ; thread tile 4 pts x 16 ch (h2 overwrites a0 region)
        const int p0 = (tid & 7) << 2, c0 = (tid >> 3) << 4;
        float acc[16][4];
        #pragma unroll
        for (int cc=0;cc<16;++cc){
            #pragma unroll
            for (int ee=0;ee<4;++ee) acc[cc][ee]=0.f;
        }
        for (int r = 0; r < 256; ++r){
            ushort4 av = *(const ushort4*)&h1p[r*SAS + p0];
            float a[4] = { b2f(av.x), b2f(av.y), b2f(av.z), b2f(av.w) };
            float4 w0 = *(const float4*)(sw2 + r*512 + c0);
            float4 w1 = *(const float4*)(sw2 + r*512 + c0 + 4);
            float4 w2 = *(const float4*)(sw2 + r*512 + c0 + 8);
            float4 w3 = *(const float4*)(sw2 + r*512 + c0 + 12);
            float w[16] = {w0.x,w0.y,w0.z,w0.w, w1.x,w1.y,w1.z,w1.w,
                           w2.x,w2.y,w2.z,w2.w, w3.x,w3.y,w3.z,w3.w};
            #pragma unroll
            for (int cc=0;cc<16;++cc){
                #pragma unroll
                for (int ee=0;ee<4;++ee) acc[cc][ee] += w[cc]*a[ee];
            }
        }
        #pragma unroll
        for (int cc=0;cc<16;++cc){
            int c = c0 + cc;
            float s = sc2[c], h = sh2[c];
            ushort4 o;
            o.x=f2b(fmaxf(acc[cc][0]*s+h,0.f)); o.y=f2b(fmaxf(acc[cc][1]*s+h,0.f));
            o.z=f2b(fmaxf(acc[cc][2]*s+h,0.f)); o.w=f2b(fmaxf(acc[cc][3]*s+h,0.f));
            *(ushort4*)&h2p[c*SAS + p0] = o;
        }
    }
    __syncthreads();

    // s3: 512 -> 1024 in two column halves; block max over 4 pts then atomic scene max
    for (int half = 0; half < 2; ++half){
        const int p0 = (tid & 7) << 2, c0 = (tid >> 3) << 4;
        const int cbase = (half << 9) + c0;
        float acc[16][4];
        #pragma unroll
        for (int cc=0;cc<16;++cc){
            #pragma unroll
            for (int ee=0;ee<4;++ee) acc[cc][ee]=0.f;
        }
        for (int r = 0; r < 512; ++r){
            ushort4 av = *(const ushort4*)&h2p[r*SAS + p0];
            float a[4] = { b2f(av.x), b2f(av.y), b2f(av.z), b2f(av.w) };
            float4 w0 = *(const float4*)(sw3 + r*1024 + cbase);
            float4 w1 = *(const float4*)(sw3 + r*1024 + cbase + 4);
            float4 w2 = *(const float4*)(sw3 + r*1024 + cbase + 8);
            float4 w3 = *(const float4*)(sw3 + r*1024 + cbase + 12);
            float w[16] = {w0.x,w0.y,w0.z,w0.w, w1.x,w1.y,w1.z,w1.w,
                           w2.x,w2.y,w2.z,w2.w, w3.x,w3.y,w3.z,w3.w};
            #pragma unroll
            for (int cc=0;cc<16;++cc){
                #pragma unroll
                for (int ee=0;ee<4;++ee) acc[cc][ee] += w[cc]*a[ee];
            }
        }
        #pragma unroll
        for (int cc=0;cc<16;++cc){
            float bias = sb3[cbase+cc];   // uniform over points: add after max
            float v = fmaxf(fmaxf(acc[cc][0], acc[cc][1]), fmaxf(acc[cc][2], acc[cc][3])) + bias;
            atomicMax(scene_map + (b << 10) + cbase + cc, fmap(v));
        }
    }
}

// ---------------------------------------------------------------- head
__global__ __launch_bounds__(128) void head1_kernel(
    const float* __restrict__ conv,
    const u32* __restrict__ xmap, const u32* __restrict__ scene_map, const int* __restrict__ qidx,
    float* __restrict__ h1out)
{
    __shared__ float ef[1280];
    const float* pw1 = conv + O_PW1; const float* pb1 = conv + O_PB1;
    const int b  = blockIdx.x >> 2;
    const int c0 = (blockIdx.x & 3) << 7;
    const int tid = threadIdx.x;
    const int q = qidx[b];
    for (int u = tid; u < 1280; u += 128){
        float v;
        if (u < 256) v = funmap(xmap[(((u32)(b*NN + q)) << 8) + u]);
        else         v = funmap(scene_map[(b << 10) + (u - 256)]);
        ef[u] = v;
    }
    __syncthreads();
    const int c = c0 + tid;
    float acc = pb1[c];
    for (int r = 0; r < 1280; ++r) acc += ef[r] * pw1[r*512 + c];
    h1out[(b << 9) + c] = fmaxf(acc, 0.f);
}

__global__ __launch_bounds__(256) void head2_kernel(
    const float* __restrict__ conv, const float* __restrict__ h1in,
    const u32* __restrict__ flagp, void* __restrict__ outv)
{
    __shared__ float h1[4][512];
    __shared__ float h2[4][256];
    const float* pw2 = conv + O_PW2; const float* pb2 = conv + O_PB2;
    const float* pw3 = conv + O_PW3; const float* pb3 = conv + O_PB3;
    const int tid = threadIdx.x;
    for (int u = tid; u < 2048; u += 256) h1[u >> 9][u & 511] = h1in[u];
    __syncthreads();
    for (int o = tid; o < 1024; o += 256){
        int b = o >> 8, c = o & 255;
        float acc = pb2[c];
        for (int r = 0; r < 512; ++r) acc += h1[b][r] * pw2[r*256 + c];
        h2[b][c] = fmaxf(acc, 0.f);
    }
    __syncthreads();
    if (tid < 64){
        int b = tid >> 4, c = tid & 15;
        float acc = pb3[c];
        for (int r = 0; r < 256; ++r) acc += h2[b][r] * pw3[r*16 + c];
        if (*flagp) ((u16*)outv)[tid] = f2b(acc);
        else        ((float*)outv)[tid] = acc;
    }
}

// ---------------------------------------------------------------- launch
extern "C" void kernel_launch(void* const* d_in, const int* in_sizes, int n_in,
                              void* d_out, int out_size, void* d_ws, size_t ws_size,
                              hipStream_t stream){
    (void)in_sizes; (void)n_in; (void)out_size; (void)ws_size;
    const int* qidx = (const int*)d_in[1];

    char* ws = (char*)d_ws;
    u32*  flag      = (u32*)ws;                          // @0
    float* conv     = (float*)(ws + 1024);               // 6.43 MB f32
    int*  knn       = (int*)(ws + 6553600);              // 1 MB
    u32*  xmap      = (u32*)(ws + 8388608);              // 16 MB
    u32*  scene_map = (u32*)(ws + 25165824);             // 16 KB
    float* h1ws     = (float*)(ws + 25182208);           // 8 KB

    Ptrs pt;
    pt.p[0] = d_in[0];
    for (int k = 1; k < N_ARR; ++k) pt.p[k] = d_in[k + 1];

    hipMemsetAsync(xmap, 0, (size_t)BB*NN*256*4 + 4096*4, stream);  // xmap+scene contiguous

    detect_kernel <<<1, 256, 0, stream>>>((const u16*)d_in[0], flag);
    convert_kernel<<<512, 256, 0, stream>>>(pt, flag, conv);
    knn_kernel <<<4096, 256, 0, stream>>>(conv, knn);
    edge_kernel<<<4096, 256, 0, stream>>>(conv, knn, xmap);
    sa_kernel  <<<512, 256, 0, stream>>>(conv, xmap, scene_map);
    head1_kernel<<<16, 128, 0, stream>>>(conv, xmap, scene_map, qidx, h1ws);
    head2_kernel<<<1, 256, 0, stream>>>(conv, h1ws, flag, (void*)d_out);
}

// Round 3
// 1183.504 us; speedup vs baseline: 3.7970x; 3.7970x over previous
//
#include <hip/hip_runtime.h>

#define BB 4
#define NN 4096
#define KK 16

typedef unsigned short u16;
typedef unsigned int   u32;
typedef unsigned long long u64;

__device__ __forceinline__ float b2f(u16 x){ return __uint_as_float(((u32)x) << 16); }
__device__ __forceinline__ u16 f2b(float f){
    u32 u = __float_as_uint(f);
    u32 r = (u + 0x7FFFu + ((u >> 16) & 1u)) >> 16;   // RNE
    return (u16)r;
}
// order-preserving f32 -> u32 map (for atomicMax-based float max)
__device__ __forceinline__ u32 fmap(float f){
    u32 u = __float_as_uint(f);
    return (u & 0x80000000u) ? ~u : (u | 0x80000000u);
}
__device__ __forceinline__ float funmap(u32 u){
    u32 v = (u & 0x80000000u) ? (u ^ 0x80000000u) : ~u;
    return __uint_as_float(v);
}

// ---------------- input normalization (runtime dtype detect: f32 vs bf16) ----
#define N_ARR 27
__device__ const int ASZ[N_ARR] = {
    49152, 384, 64, 64, 64, 8192, 128, 128, 128, 32768, 256,
    66304, 256, 256, 256, 131072, 512, 512, 512, 524288, 1024,
    655360, 512, 131072, 256, 4096, 16 };
__device__ const int AOFF[N_ARR] = {
    0, 49152, 49536, 49600, 49664, 49728, 57920, 58048, 58176, 58304, 91072,
    91328, 157632, 157888, 158144, 158400, 289472, 289984, 290496, 291008, 815296,
    816320, 1471680, 1472192, 1603264, 1603520, 1607616 };

struct Ptrs { const void* p[N_ARR]; };

#define O_POS 0
#define O_CW1 49152
#define O_CB1 49536
#define O_CG1 49600
#define O_CS1 49664
#define O_CW2 49728
#define O_CB2 57920
#define O_CG2 58048
#define O_CS2 58176
#define O_CW3 58304
#define O_CB3 91072
#define O_SW1 91328
#define O_SB1 157632
#define O_SG1 157888
#define O_SS1 158144
#define O_SW2 158400
#define O_SB2 289472
#define O_SG2 289984
#define O_SS2 290496
#define O_SW3 291008
#define O_SB3 815296
#define O_PW1 816320
#define O_PB1 1471680
#define O_PW2 1472192
#define O_PB2 1603264
#define O_PW3 1603520
#define O_PB3 1607616

__global__ void detect_kernel(const u16* __restrict__ pos_u16, u32* __restrict__ flag){
    __shared__ int cnt;
    if (threadIdx.x == 0) cnt = 0;
    __syncthreads();
    int c = 0;
    #pragma unroll
    for (int s = 0; s < 4; ++s){
        u16 u = pos_u16[2*(threadIdx.x*4 + s)];
        int e = (u >> 7) & 0xFF;
        c += (e >= 0x68 && e <= 0x82) ? 1 : 0;
    }
    atomicAdd(&cnt, c);
    __syncthreads();
    if (threadIdx.x == 0) *flag = (cnt >= 512) ? 1u : 0u;   // 1 = bf16 inputs
}

__global__ __launch_bounds__(256) void convert_kernel(Ptrs pt, const u32* __restrict__ flagp,
                                                      float* __restrict__ dst){
    const bool isbf = (*flagp != 0);
    const int T = gridDim.x * 256;
    const int g = blockIdx.x * 256 + threadIdx.x;
    #pragma unroll
    for (int a = 0; a < N_ARR; ++a){
        const int sz = ASZ[a], off = AOFF[a];
        if (isbf){
            const u16* s = (const u16*)pt.p[a];
            for (int i = g; i < sz; i += T) dst[off + i] = b2f(s[i]);
        } else {
            const float* s = (const float*)pt.p[a];
            for (int i = g; i < sz; i += T) dst[off + i] = s[i];
        }
    }
}

// ---------------------------------------------------------------- kNN
__global__ __launch_bounds__(256) void knn_kernel(const float* __restrict__ conv,
                                                  int* __restrict__ knn_out){
    __shared__ float sx[NN], sy[NN], sz[NN];
    const float* posf = conv + O_POS;
    const int b  = blockIdx.x >> 10;
    const int i0 = (blockIdx.x & 1023) << 2;
    const int tid = threadIdx.x;
    for (int t = tid; t < NN; t += 256){
        const float* p = posf + ((size_t)(b*NN + t))*3;
        sx[t] = p[0]; sy[t] = p[1]; sz[t] = p[2];
    }
    __syncthreads();
    const int lane = tid & 63;
    const int i = i0 + (tid >> 6);
    const float pix = sx[i], piy = sy[i], piz = sz[i];

    float d[KK]; int id[KK];
    #pragma unroll
    for (int t = 0; t < KK; ++t){
        int j = lane + (t << 6);
        float dx = pix - sx[j], dy = piy - sy[j], dz = piz - sz[j];
        d[t] = __fadd_rn(__fadd_rn(__fmul_rn(dx,dx), __fmul_rn(dy,dy)), __fmul_rn(dz,dz));
        id[t] = j;
    }
    float dmax = d[0]; int amax = 0;
    #pragma unroll
    for (int p = 1; p < KK; ++p){ bool c = d[p] > dmax; dmax = c ? d[p] : dmax; amax = c ? p : amax; }

    for (int t = KK; t < 64; ++t){
        int j = lane + (t << 6);
        float dx = pix - sx[j], dy = piy - sy[j], dz = piz - sz[j];
        float d2 = __fadd_rn(__fadd_rn(__fmul_rn(dx,dx), __fmul_rn(dy,dy)), __fmul_rn(dz,dz));
        if (d2 < dmax){           // strict <: earlier index wins ties
            #pragma unroll
            for (int p = 0; p < KK; ++p){ bool c = (p == amax); d[p] = c ? d2 : d[p]; id[p] = c ? j : id[p]; }
            dmax = d[0]; amax = 0;
            #pragma unroll
            for (int p = 1; p < KK; ++p){ bool c = d[p] > dmax; dmax = c ? d[p] : dmax; amax = c ? p : amax; }
        }
    }
    u64 key[KK];
    #pragma unroll
    for (int p = 0; p < KK; ++p) key[p] = (((u64)__float_as_uint(d[p])) << 32) | (u32)id[p];
    int* outp = knn_out + ((size_t)(b*NN + i))*KK;
    for (int r = 0; r < KK; ++r){
        u64 m = key[0];
        #pragma unroll
        for (int p = 1; p < KK; ++p) m = key[p] < m ? key[p] : m;
        #pragma unroll
        for (int off = 32; off > 0; off >>= 1){
            u64 o = __shfl_xor(m, off);
            m = o < m ? o : m;
        }
        if (lane == 0) outp[r] = (int)(u32)(m & 0xFFFFFFFFu);
        #pragma unroll
        for (int p = 0; p < KK; ++p) if (key[p] == m) key[p] = ~0ull;
    }
}

// ---------------------------------------------------------------- CSR build (invert kNN graph)
__global__ __launch_bounds__(256) void cnt_kernel(const int* __restrict__ knn, u32* __restrict__ deg){
    int e = blockIdx.x*256 + threadIdx.x;
    int b = e >> 16;
    int t = (b << 12) + knn[e];
    atomicAdd(deg + t, 1u);
}

__global__ __launch_bounds__(1024) void scan_kernel(const u32* __restrict__ deg,
                                                    int* __restrict__ rowstart, u32* __restrict__ cursor){
    __shared__ int lsum[1024];
    const int tid = threadIdx.x;
    const int base = tid * 16;
    int loc[16]; int s = 0;
    #pragma unroll
    for (int q = 0; q < 16; ++q){ loc[q] = (int)deg[base+q]; s += loc[q]; }
    lsum[tid] = s;
    __syncthreads();
    int acc = s;
    for (int ofs = 1; ofs < 1024; ofs <<= 1){
        int t = (tid >= ofs) ? lsum[tid-ofs] : 0;
        __syncthreads();
        acc += t; lsum[tid] = acc;
        __syncthreads();
    }
    int excl = acc - s;
    #pragma unroll
    for (int q = 0; q < 16; ++q){
        rowstart[base+q] = excl; cursor[base+q] = (u32)excl; excl += loc[q];
    }
    if (tid == 1023) rowstart[16384] = excl;
}

__global__ __launch_bounds__(256) void fill_kernel(const int* __restrict__ knn,
                                                   u32* __restrict__ cursor, int* __restrict__ csr){
    int e = blockIdx.x*256 + threadIdx.x;
    int b = e >> 16;
    int t = (b << 12) + knn[e];
    u32 pos = atomicAdd(cursor + t, 1u);
    csr[pos] = e;
}

// ---------------------------------------------------------------- edge MLP + in-block segment max
// Block owns 16 whole targets (all their in-edges, CSR-contiguous). Zero global atomics.
__global__ __launch_bounds__(256, 2) void edge_kernel(
    const float* __restrict__ conv, const int* __restrict__ knn,
    const int* __restrict__ rowstart, const int* __restrict__ csr,
    float* __restrict__ xf)
{
    __shared__ float in6[6][64];
    __shared__ int   lts[64];
    __shared__ int   rs_l[17];
    __shared__ __align__(16) u16 h1s[64][64];     // [ch][edge]
    __shared__ __align__(16) u16 h2s[128][64];    // [ch][edge]
    __shared__ __align__(16) u16 h3s[64*256];     // [edge][ch]
    __shared__ float sc1[64], sh1[64], sc2[128], sh2[128];

    const float* posf = conv + O_POS;
    const float* cw1 = conv + O_CW1; const float* cb1 = conv + O_CB1;
    const float* cg1 = conv + O_CG1; const float* cs1 = conv + O_CS1;
    const float* cw2 = conv + O_CW2; const float* cb2 = conv + O_CB2;
    const float* cg2 = conv + O_CG2; const float* cs2 = conv + O_CS2;
    const float* cw3 = conv + O_CW3; const float* cb3 = conv + O_CB3;

    const int tid = threadIdx.x;
    const int t0  = blockIdx.x << 4;      // first of 16 targets
    const int b   = t0 >> 12;

    if (tid < 64){ float g1 = cg1[tid]; sc1[tid]=g1; sh1[tid]=cb1[tid]*g1 + cs1[tid]; }
    if (tid < 128){ float g2 = cg2[tid]; sc2[tid]=g2; sh2[tid]=cb2[tid]*g2 + cs2[tid]; }
    if (tid < 17) rs_l[tid] = rowstart[t0 + tid];
    __syncthreads();
    const int segstart = rs_l[0], segend = rs_l[16];
    const int nchunk = (segend - segstart + 63) >> 6;

    const int e0 = (tid & 15) << 2;
    const int c0_3 = (tid >> 4) << 4;      // layer-3 channel base
    float bs3[16];
    #pragma unroll
    for (int q = 0; q < 16; ++q) bs3[q] = cb3[c0_3 + q];

    const int c = tid;                     // reduction channel
    float xr[16];
    #pragma unroll
    for (int q = 0; q < 16; ++q) xr[q] = -3.0e38f;
    int curl = -1; float run = 0.f;

    for (int ch = 0; ch < nchunk; ++ch){
        __syncthreads();   // previous chunk's h3s/in6 readers done
        if (tid < 64){
            int gpos = segstart + (ch << 6) + tid;
            int l = -1;
            float ax=0,ay=0,az=0,dx=0,dy=0,dz=0;
            if (gpos < segend){
                l = 0;
                #pragma unroll
                for (int q = 1; q < 16; ++q) l += (gpos >= rs_l[q]) ? 1 : 0;
                int e = csr[gpos];
                int i = (e >> 4) & (NN - 1);
                int j = knn[e];
                const float* pi = posf + ((size_t)(b*NN + i))*3;
                const float* pj = posf + ((size_t)(b*NN + j))*3;
                ax = pi[0]; ay = pi[1]; az = pi[2];
                dx = ax - pj[0]; dy = ay - pj[1]; dz = az - pj[2];
            }
            lts[tid] = l;
            in6[0][tid]=ax; in6[1][tid]=ay; in6[2][tid]=az;
            in6[3][tid]=dx; in6[4][tid]=dy; in6[5][tid]=dz;
        }
        __syncthreads();

        { // layer 1: wave w -> channels w*16..+15, lane = edge
            const int lane = tid & 63, w = tid >> 6;
            float a0=in6[0][lane], a1=in6[1][lane], a2=in6[2][lane],
                  a3=in6[3][lane], a4=in6[4][lane], a5=in6[5][lane];
            #pragma unroll
            for (int ci = 0; ci < 16; ++ci){
                int cc = (w << 4) + ci;
                float acc = a0*cw1[cc]     + a1*cw1[64+cc]  + a2*cw1[128+cc]
                          + a3*cw1[192+cc] + a4*cw1[256+cc] + a5*cw1[320+cc];
                acc = fmaxf(acc*sc1[cc] + sh1[cc], 0.f);
                h1s[cc][lane] = f2b(acc);
            }
        }
        __syncthreads();

        { // layer 2: thread tile 4 edges x 8 channels
            const int c0 = (tid >> 4) << 3;
            float acc[8][4];
            #pragma unroll
            for (int cc=0;cc<8;++cc){
                #pragma unroll
                for (int ee=0;ee<4;++ee) acc[cc][ee]=0.f;
            }
            for (int r = 0; r < 64; ++r){
                ushort4 av = *(const ushort4*)&h1s[r][e0];
                float a[4] = { b2f(av.x), b2f(av.y), b2f(av.z), b2f(av.w) };
                float4 wa = *(const float4*)(cw2 + r*128 + c0);
                float4 wb = *(const float4*)(cw2 + r*128 + c0 + 4);
                float w[8] = {wa.x,wa.y,wa.z,wa.w, wb.x,wb.y,wb.z,wb.w};
                #pragma unroll
                for (int cc=0;cc<8;++cc){
                    #pragma unroll
                    for (int ee=0;ee<4;++ee) acc[cc][ee] += w[cc]*a[ee];
                }
            }
            #pragma unroll
            for (int cc=0;cc<8;++cc){
                int cg = c0 + cc;
                float s = sc2[cg], h = sh2[cg];
                ushort4 o;
                o.x = f2b(fmaxf(acc[cc][0]*s+h,0.f));
                o.y = f2b(fmaxf(acc[cc][1]*s+h,0.f));
                o.z = f2b(fmaxf(acc[cc][2]*s+h,0.f));
                o.w = f2b(fmaxf(acc[cc][3]*s+h,0.f));
                *(ushort4*)&h2s[cg][e0] = o;
            }
        }
        __syncthreads();

        { // layer 3: thread tile 4 edges x 16 channels -> h3s[edge][ch] (+bias)
            float acc[16][4];
            #pragma unroll
            for (int cc=0;cc<16;++cc){
                #pragma unroll
                for (int ee=0;ee<4;++ee) acc[cc][ee]=0.f;
            }
            for (int r = 0; r < 128; ++r){
                ushort4 av = *(const ushort4*)&h2s[r][e0];
                float a[4] = { b2f(av.x), b2f(av.y), b2f(av.z), b2f(av.w) };
                float4 w0 = *(const float4*)(cw3 + r*256 + c0_3);
                float4 w1 = *(const float4*)(cw3 + r*256 + c0_3 + 4);
                float4 w2 = *(const float4*)(cw3 + r*256 + c0_3 + 8);
                float4 w3 = *(const float4*)(cw3 + r*256 + c0_3 + 12);
                float w[16] = {w0.x,w0.y,w0.z,w0.w, w1.x,w1.y,w1.z,w1.w,
                               w2.x,w2.y,w2.z,w2.w, w3.x,w3.y,w3.z,w3.w};
                #pragma unroll
                for (int cc=0;cc<16;++cc){
                    #pragma unroll
                    for (int ee=0;ee<4;++ee) acc[cc][ee] += w[cc]*a[ee];
                }
            }
            #pragma unroll
            for (int ee=0;ee<4;++ee){
                u32 pk[8];
                #pragma unroll
                for (int q=0;q<8;++q){
                    float v0 = acc[2*q][ee]   + bs3[2*q];
                    float v1 = acc[2*q+1][ee] + bs3[2*q+1];
                    pk[q] = (u32)f2b(v0) | (((u32)f2b(v1)) << 16);
                }
                uint4* dst = (uint4*)&h3s[(e0+ee)*256 + c0_3];
                dst[0] = make_uint4(pk[0],pk[1],pk[2],pk[3]);
                dst[1] = make_uint4(pk[4],pk[5],pk[6],pk[7]);
            }
        }
        __syncthreads();

        // segmented max over this chunk: thread owns channel c; branch is wave-uniform
        for (int pos = 0; pos < 64; ++pos){
            int l = lts[pos];
            float v = b2f(h3s[pos*256 + c]);
            if (l != curl){
                if (curl >= 0){
                    #pragma unroll
                    for (int q=0;q<16;++q) if (q == curl) xr[q] = fmaxf(xr[q], run);
                }
                curl = l; run = v;
            } else {
                run = fmaxf(run, v);
            }
        }
    }
    if (curl >= 0){
        #pragma unroll
        for (int q=0;q<16;++q) if (q == curl) xr[q] = fmaxf(xr[q], run);
    }
    #pragma unroll
    for (int q=0;q<16;++q) xf[((size_t)(t0+q))*256 + c] = xr[q];
}

// ---------------------------------------------------------------- GlobalSA MLP + scene max
#define SAS 36
__global__ __launch_bounds__(256) void sa_kernel(
    const float* __restrict__ conv, const float* __restrict__ xf,
    u32* __restrict__ scene_map)
{
    __shared__ __align__(16) char smem[61440];
    u16* h1p = (u16*)smem;                 // [256][36] bf16 (18432 B); reused as f32 sred in s3
    u16* a0p = (u16*)(smem + 18432);       // [259][36] bf16
    u16* h2p = (u16*)(smem + 18432);       // [512][36] bf16 (reuses a0)
    float* sc1 = (float*)(smem + 55296);
    float* sh1 = sc1 + 256;
    float* sc2 = sh1 + 256;
    float* sh2 = sc2 + 512;

    const float* posf = conv + O_POS;
    const float* sw1 = conv + O_SW1; const float* sb1 = conv + O_SB1;
    const float* sg1 = conv + O_SG1; const float* ss1 = conv + O_SS1;
    const float* sw2 = conv + O_SW2; const float* sb2 = conv + O_SB2;
    const float* sg2 = conv + O_SG2; const float* ss2 = conv + O_SS2;
    const float* sw3 = conv + O_SW3; const float* sb3 = conv + O_SB3;

    const int tid = threadIdx.x;
    const int b  = blockIdx.x >> 7;
    const int n0 = (blockIdx.x & 127) << 5;

    for (int u = tid; u < 32*256; u += 256){
        int p = u >> 8, cc = u & 255;
        float f = xf[(((size_t)(b*NN + n0 + p)) << 8) + cc];
        a0p[cc*SAS + p] = f2b(f);
    }
    if (tid < 96){
        int p = tid & 31, cc = tid >> 5;
        a0p[(256+cc)*SAS + p] = f2b(posf[((size_t)(b*NN + n0 + p))*3 + cc]);
    }
    if (tid < 256){ float g = sg1[tid]; sc1[tid]=g; sh1[tid]=sb1[tid]*g + ss1[tid]; }
    for (int u = tid; u < 512; u += 256){ float g=sg2[u]; sc2[u]=g; sh2[u]=sb2[u]*g + ss2[u]; }
    __syncthreads();

    { // s1: 259 -> 256
        const int p0 = (tid & 7) << 2, c0 = (tid >> 3) << 3;
        float acc[8][4];
        #pragma unroll
        for (int cc=0;cc<8;++cc){
            #pragma unroll
            for (int ee=0;ee<4;++ee) acc[cc][ee]=0.f;
        }
        for (int r = 0; r < 259; ++r){
            ushort4 av = *(const ushort4*)&a0p[r*SAS + p0];
            float a[4] = { b2f(av.x), b2f(av.y), b2f(av.z), b2f(av.w) };
            float4 wa = *(const float4*)(sw1 + r*256 + c0);
            float4 wb = *(const float4*)(sw1 + r*256 + c0 + 4);
            float w[8] = {wa.x,wa.y,wa.z,wa.w, wb.x,wb.y,wb.z,wb.w};
            #pragma unroll
            for (int cc=0;cc<8;++cc){
                #pragma unroll
                for (int ee=0;ee<4;++ee) acc[cc][ee] += w[cc]*a[ee];
            }
        }
        #pragma unroll
        for (int cc=0;cc<8;++cc){
            int cg = c0 + cc;
            float s = sc1[cg], h = sh1[cg];
            ushort4 o;
            o.x=f2b(fmaxf(acc[cc][0]*s+h,0.f)); o.y=f2b(fmaxf(acc[cc][1]*s+h,0.f));
            o.z=f2b(fmaxf(acc[cc][2]*s+h,0.f)); o.w=f2b(fmaxf(acc[cc][3]*s+h,0.f));
            *(ushort4*)&h1p[cg*SAS + p0] = o;
        }
    }
    __syncthreads();

    { // s2: 256 -> 512
        const int p0 = (tid & 7) << 2, c0 = (tid >> 3) << 4;
        float acc[16][4];
        #pragma unroll
        for (int cc=0;cc<16;++cc){
            #pragma unroll
            for (int ee=0;ee<4;++ee) acc[cc][ee]=0.f;
        }
        for (int r = 0; r < 256; ++r){
            ushort4 av = *(const ushort4*)&h1p[r*SAS + p0];
            float a[4] = { b2f(av.x), b2f(av.y), b2f(av.z), b2f(av.w) };
            float4 w0 = *(const float4*)(sw2 + r*512 + c0);
            float4 w1 = *(const float4*)(sw2 + r*512 + c0 + 4);
            float4 w2 = *(const float4*)(sw2 + r*512 + c0 + 8);
            float4 w3 = *(const float4*)(sw2 + r*512 + c0 + 12);
            float w[16] = {w0.x,w0.y,w0.z,w0.w, w1.x,w1.y,w1.z,w1.w,
                           w2.x,w2.y,w2.z,w2.w, w3.x,w3.y,w3.z,w3.w};
            #pragma unroll
            for (int cc=0;cc<16;++cc){
                #pragma unroll
                for (int ee=0;ee<4;++ee) acc[cc][ee] += w[cc]*a[ee];
            }
        }
        #pragma unroll
        for (int cc=0;cc<16;++cc){
            int cg = c0 + cc;
            float s = sc2[cg], h = sh2[cg];
            ushort4 o;
            o.x=f2b(fmaxf(acc[cc][0]*s+h,0.f)); o.y=f2b(fmaxf(acc[cc][1]*s+h,0.f));
            o.z=f2b(fmaxf(acc[cc][2]*s+h,0.f)); o.w=f2b(fmaxf(acc[cc][3]*s+h,0.f));
            *(ushort4*)&h2p[cg*SAS + p0] = o;
        }
    }
    __syncthreads();

    // s3: 512 -> 1024, LDS pre-reduce over the 8 point-groups, 1 atomic/channel
    for (int half = 0; half < 2; ++half){
        const int p0 = (tid & 7) << 2, c0 = (tid >> 3) << 4;
        const int cbase = (half << 9) + c0;
        float acc[16][4];
        #pragma unroll
        for (int cc=0;cc<16;++cc){
            #pragma unroll
            for (int ee=0;ee<4;++ee) acc[cc][ee]=0.f;
        }
        for (int r = 0; r < 512; ++r){
            ushort4 av = *(const ushort4*)&h2p[r*SAS + p0];
            float a[4] = { b2f(av.x), b2f(av.y), b2f(av.z), b2f(av.w) };
            float4 w0 = *(const float4*)(sw3 + r*1024 + cbase);
            float4 w1 = *(const float4*)(sw3 + r*1024 + cbase + 4);
            float4 w2 = *(const float4*)(sw3 + r*1024 + cbase + 8);
            float4 w3 = *(const float4*)(sw3 + r*1024 + cbase + 12);
            float w[16] = {w0.x,w0.y,w0.z,w0.w, w1.x,w1.y,w1.z,w1.w,
                           w2.x,w2.y,w2.z,w2.w, w3.x,w3.y,w3.z,w3.w};
            #pragma unroll
            for (int cc=0;cc<16;++cc){
                #pragma unroll
                for (int ee=0;ee<4;++ee) acc[cc][ee] += w[cc]*a[ee];
            }
        }
        float* sred = (float*)smem;   // [8][512] f32 = 16 KB (h1p region, dead now)
        #pragma unroll
        for (int cc=0;cc<16;++cc){
            float v = fmaxf(fmaxf(acc[cc][0], acc[cc][1]), fmaxf(acc[cc][2], acc[cc][3]));
            sred[(tid & 7)*512 + c0 + cc] = v;
        }
        __syncthreads();
        for (int ci = tid; ci < 512; ci += 256){
            float m = sred[ci];
            #pragma unroll
            for (int r = 1; r < 8; ++r) m = fmaxf(m, sred[r*512 + ci]);
            float v = m + sb3[(half << 9) + ci];
            atomicMax(scene_map + (b << 10) + (half << 9) + ci, fmap(v));
        }
        __syncthreads();
    }
}

// ---------------------------------------------------------------- head
__global__ __launch_bounds__(128) void head1_kernel(
    const float* __restrict__ conv,
    const float* __restrict__ xf, const u32* __restrict__ scene_map, const int* __restrict__ qidx,
    float* __restrict__ h1out)
{
    __shared__ float ef[1280];
    const float* pw1 = conv + O_PW1; const float* pb1 = conv + O_PB1;
    const int b  = blockIdx.x >> 2;
    const int c0 = (blockIdx.x & 3) << 7;
    const int tid = threadIdx.x;
    const int q = qidx[b];
    for (int u = tid; u < 1280; u += 128){
        float v;
        if (u < 256) v = xf[(((size_t)(b*NN + q)) << 8) + u];
        else         v = funmap(scene_map[(b << 10) + (u - 256)]);
        ef[u] = v;
    }
    __syncthreads();
    const int c = c0 + tid;
    float acc = pb1[c];
    for (int r = 0; r < 1280; ++r) acc += ef[r] * pw1[r*512 + c];
    h1out[(b << 9) + c] = fmaxf(acc, 0.f);
}

__global__ __launch_bounds__(256) void head2_kernel(
    const float* __restrict__ conv, const float* __restrict__ h1in,
    const u32* __restrict__ flagp, void* __restrict__ outv)
{
    __shared__ float h1[4][512];
    __shared__ float h2[4][256];
    const float* pw2 = conv + O_PW2; const float* pb2 = conv + O_PB2;
    const float* pw3 = conv + O_PW3; const float* pb3 = conv + O_PB3;
    const int tid = threadIdx.x;
    for (int u = tid; u < 2048; u += 256) h1[u >> 9][u & 511] = h1in[u];
    __syncthreads();
    for (int o = tid; o < 1024; o += 256){
        int b = o >> 8, c = o & 255;
        float acc = pb2[c];
        for (int r = 0; r < 512; ++r) acc += h1[b][r] * pw2[r*256 + c];
        h2[b][c] = fmaxf(acc, 0.f);
    }
    __syncthreads();
    if (tid < 64){
        int b = tid >> 4, c = tid & 15;
        float acc = pb3[c];
        for (int r = 0; r < 256; ++r) acc += h2[b][r] * pw3[r*16 + c];
        if (*flagp) ((u16*)outv)[tid] = f2b(acc);
        else        ((float*)outv)[tid] = acc;
    }
}

// ---------------------------------------------------------------- launch
extern "C" void kernel_launch(void* const* d_in, const int* in_sizes, int n_in,
                              void* d_out, int out_size, void* d_ws, size_t ws_size,
                              hipStream_t stream){
    (void)in_sizes; (void)n_in; (void)out_size; (void)ws_size;
    const int* qidx = (const int*)d_in[1];

    char* ws = (char*)d_ws;
    u32*  flag      = (u32*)ws;                       // @0
    float* conv     = (float*)(ws + 1024);            // 6.43 MB f32
    int*  knn       = (int*)(ws + 6553600);           // 1 MB
    u32*  deg       = (u32*)(ws + 7602176);           // 64 KB
    u32*  scene_map = (u32*)(ws + 7667712);           // 16 KB   (deg+scene memset together)
    int*  rowstart  = (int*)(ws + 7684096);           // 64 KB + 4
    u32*  cursor    = (u32*)(ws + 7749760);           // 64 KB
    int*  csr       = (int*)(ws + 7815296);           // 1 MB
    float* xf       = (float*)(ws + 8863872);         // 16 MB  [B*N, 256] f32
    float* h1ws     = (float*)(ws + 25641088);        // 8 KB

    Ptrs pt;
    pt.p[0] = d_in[0];
    for (int k = 1; k < N_ARR; ++k) pt.p[k] = d_in[k + 1];

    hipMemsetAsync(ws + 7602176, 0, 81920, stream);   // deg + scene_map

    detect_kernel <<<1, 256, 0, stream>>>((const u16*)d_in[0], flag);
    convert_kernel<<<512, 256, 0, stream>>>(pt, flag, conv);
    knn_kernel <<<4096, 256, 0, stream>>>(conv, knn);
    cnt_kernel <<<1024, 256, 0, stream>>>(knn, deg);
    scan_kernel<<<1, 1024, 0, stream>>>(deg, rowstart, cursor);
    fill_kernel<<<1024, 256, 0, stream>>>(knn, cursor, csr);
    edge_kernel<<<1024, 256, 0, stream>>>(conv, knn, rowstart, csr, xf);
    sa_kernel  <<<512, 256, 0, stream>>>(conv, xf, scene_map);
    head1_kernel<<<16, 128, 0, stream>>>(conv, xf, scene_map, qidx, h1ws);
    head2_kernel<<<1, 256, 0, stream>>>(conv, h1ws, flag, (void*)d_out);
}

// Round 4
// 901.992 us; speedup vs baseline: 4.9821x; 1.3121x over previous
//
#include <hip/hip_runtime.h>

#define BB 4
#define NN 4096
#define KK 16

typedef unsigned short u16;
typedef unsigned int   u32;
typedef unsigned long long u64;

typedef __attribute__((ext_vector_type(8))) short bf16x8;
typedef __attribute__((ext_vector_type(4))) float f32x4;

__device__ __forceinline__ float b2f(u16 x){ return __uint_as_float(((u32)x) << 16); }
__device__ __forceinline__ u16 f2b(float f){
    u32 u = __float_as_uint(f);
    u32 r = (u + 0x7FFFu + ((u >> 16) & 1u)) >> 16;   // RNE
    return (u16)r;
}
__device__ __forceinline__ u32 fmap(float f){
    u32 u = __float_as_uint(f);
    return (u & 0x80000000u) ? ~u : (u | 0x80000000u);
}
__device__ __forceinline__ float funmap(u32 u){
    u32 v = (u & 0x80000000u) ? (u ^ 0x80000000u) : ~u;
    return __uint_as_float(v);
}

// ---------------- input normalization (runtime dtype detect: f32 vs bf16) ----
#define N_ARR 27
__device__ const int ASZ[N_ARR] = {
    49152, 384, 64, 64, 64, 8192, 128, 128, 128, 32768, 256,
    66304, 256, 256, 256, 131072, 512, 512, 512, 524288, 1024,
    655360, 512, 131072, 256, 4096, 16 };
__device__ const int AOFF[N_ARR] = {
    0, 49152, 49536, 49600, 49664, 49728, 57920, 58048, 58176, 58304, 91072,
    91328, 157632, 157888, 158144, 158400, 289472, 289984, 290496, 291008, 815296,
    816320, 1471680, 1472192, 1603264, 1603520, 1607616 };

struct Ptrs { const void* p[N_ARR]; };

#define O_POS 0
#define O_CW1 49152
#define O_CB1 49536
#define O_CG1 49600
#define O_CS1 49664
#define O_CW2 49728
#define O_CB2 57920
#define O_CG2 58048
#define O_CS2 58176
#define O_CW3 58304
#define O_CB3 91072
#define O_SW1 91328
#define O_SB1 157632
#define O_SG1 157888
#define O_SS1 158144
#define O_SW2 158400
#define O_SB2 289472
#define O_SG2 289984
#define O_SS2 290496
#define O_SW3 291008
#define O_SB3 815296
#define O_PW1 816320
#define O_PB1 1471680
#define O_PW2 1472192
#define O_PB2 1603264
#define O_PW3 1603520
#define O_PB3 1607616

__global__ void detect_kernel(const u16* __restrict__ pos_u16, u32* __restrict__ flag){
    __shared__ int cnt;
    if (threadIdx.x == 0) cnt = 0;
    __syncthreads();
    int c = 0;
    #pragma unroll
    for (int s = 0; s < 4; ++s){
        u16 u = pos_u16[2*(threadIdx.x*4 + s)];
        int e = (u >> 7) & 0xFF;
        c += (e >= 0x68 && e <= 0x82) ? 1 : 0;
    }
    atomicAdd(&cnt, c);
    __syncthreads();
    if (threadIdx.x == 0) *flag = (cnt >= 512) ? 1u : 0u;   // 1 = bf16 inputs
}

__global__ __launch_bounds__(256) void convert_kernel(Ptrs pt, const u32* __restrict__ flagp,
                                                      float* __restrict__ dst){
    const bool isbf = (*flagp != 0);
    const int T = gridDim.x * 256;
    const int g = blockIdx.x * 256 + threadIdx.x;
    #pragma unroll
    for (int a = 0; a < N_ARR; ++a){
        const int sz = ASZ[a], off = AOFF[a];
        if (isbf){
            const u16* s = (const u16*)pt.p[a];
            for (int i = g; i < sz; i += T) dst[off + i] = b2f(s[i]);
        } else {
            const float* s = (const float*)pt.p[a];
            for (int i = g; i < sz; i += T) dst[off + i] = s[i];
        }
    }
}

// bf16 copies of cw2 (64x128) and cw3 (128x256) for MFMA B-fragments
__global__ __launch_bounds__(256) void wconv_kernel(const float* __restrict__ conv,
                                                    u16* __restrict__ wb2, u16* __restrict__ wb3){
    const int T = gridDim.x * 256;
    for (int i = blockIdx.x*256 + threadIdx.x; i < 8192 + 32768; i += T){
        if (i < 8192) wb2[i] = f2b(conv[O_CW2 + i]);
        else          wb3[i - 8192] = f2b(conv[O_CW3 + (i - 8192)]);
    }
}

// ---------------------------------------------------------------- kNN
__global__ __launch_bounds__(256) void knn_kernel(const float* __restrict__ conv,
                                                  int* __restrict__ knn_out){
    __shared__ float sx[NN], sy[NN], sz[NN];
    const float* posf = conv + O_POS;
    const int b  = blockIdx.x >> 10;
    const int i0 = (blockIdx.x & 1023) << 2;
    const int tid = threadIdx.x;
    for (int t = tid; t < NN; t += 256){
        const float* p = posf + ((size_t)(b*NN + t))*3;
        sx[t] = p[0]; sy[t] = p[1]; sz[t] = p[2];
    }
    __syncthreads();
    const int lane = tid & 63;
    const int i = i0 + (tid >> 6);
    const float pix = sx[i], piy = sy[i], piz = sz[i];

    float d[KK]; int id[KK];
    #pragma unroll
    for (int t = 0; t < KK; ++t){
        int j = lane + (t << 6);
        float dx = pix - sx[j], dy = piy - sy[j], dz = piz - sz[j];
        d[t] = __fadd_rn(__fadd_rn(__fmul_rn(dx,dx), __fmul_rn(dy,dy)), __fmul_rn(dz,dz));
        id[t] = j;
    }
    float dmax = d[0]; int amax = 0;
    #pragma unroll
    for (int p = 1; p < KK; ++p){ bool c = d[p] > dmax; dmax = c ? d[p] : dmax; amax = c ? p : amax; }

    for (int t = KK; t < 64; ++t){
        int j = lane + (t << 6);
        float dx = pix - sx[j], dy = piy - sy[j], dz = piz - sz[j];
        float d2 = __fadd_rn(__fadd_rn(__fmul_rn(dx,dx), __fmul_rn(dy,dy)), __fmul_rn(dz,dz));
        if (d2 < dmax){
            #pragma unroll
            for (int p = 0; p < KK; ++p){ bool c = (p == amax); d[p] = c ? d2 : d[p]; id[p] = c ? j : id[p]; }
            dmax = d[0]; amax = 0;
            #pragma unroll
            for (int p = 1; p < KK; ++p){ bool c = d[p] > dmax; dmax = c ? d[p] : dmax; amax = c ? p : amax; }
        }
    }
    u64 key[KK];
    #pragma unroll
    for (int p = 0; p < KK; ++p) key[p] = (((u64)__float_as_uint(d[p])) << 32) | (u32)id[p];
    int* outp = knn_out + ((size_t)(b*NN + i))*KK;
    for (int r = 0; r < KK; ++r){
        u64 m = key[0];
        #pragma unroll
        for (int p = 1; p < KK; ++p) m = key[p] < m ? key[p] : m;
        #pragma unroll
        for (int off = 32; off > 0; off >>= 1){
            u64 o = __shfl_xor(m, off);
            m = o < m ? o : m;
        }
        if (lane == 0) outp[r] = (int)(u32)(m & 0xFFFFFFFFu);
        #pragma unroll
        for (int p = 0; p < KK; ++p) if (key[p] == m) key[p] = ~0ull;
    }
}

// ---------------------------------------------------------------- CSR build
__global__ __launch_bounds__(256) void cnt_kernel(const int* __restrict__ knn, u32* __restrict__ deg){
    int e = blockIdx.x*256 + threadIdx.x;
    int b = e >> 16;
    int t = (b << 12) + knn[e];
    atomicAdd(deg + t, 1u);
}

__global__ __launch_bounds__(1024) void scan_kernel(const u32* __restrict__ deg,
                                                    int* __restrict__ rowstart, u32* __restrict__ cursor){
    __shared__ int lsum[1024];
    const int tid = threadIdx.x;
    const int base = tid * 16;
    int loc[16]; int s = 0;
    #pragma unroll
    for (int q = 0; q < 16; ++q){ loc[q] = (int)deg[base+q]; s += loc[q]; }
    lsum[tid] = s;
    __syncthreads();
    int acc = s;
    for (int ofs = 1; ofs < 1024; ofs <<= 1){
        int t = (tid >= ofs) ? lsum[tid-ofs] : 0;
        __syncthreads();
        acc += t; lsum[tid] = acc;
        __syncthreads();
    }
    int excl = acc - s;
    #pragma unroll
    for (int q = 0; q < 16; ++q){
        rowstart[base+q] = excl; cursor[base+q] = (u32)excl; excl += loc[q];
    }
    if (tid == 1023) rowstart[16384] = excl;
}

__global__ __launch_bounds__(256) void fill_kernel(const int* __restrict__ knn,
                                                   u32* __restrict__ cursor, int* __restrict__ csr){
    int e = blockIdx.x*256 + threadIdx.x;
    int b = e >> 16;
    int t = (b << 12) + knn[e];
    u32 pos = atomicAdd(cursor + t, 1u);
    csr[pos] = e;
}

// ---------------------------------------------------------------- edge MLP (MFMA) + segment max
// LDS A-fragment read with XOR bank swizzle; row-major [row][k] bf16, rowstride in u16
__device__ __forceinline__ bf16x8 ldfrag(const u16* h, int row, int kofs, int rowstride){
    u32 byte = (u32)((row*rowstride + kofs)*2) ^ (u32)((row & 7) << 4);
    return *(const bf16x8*)((const char*)h + byte);
}
__device__ __forceinline__ void st16(u16* h, int row, int col, int rowstride, float v){
    u32 byte = (u32)((row*rowstride + col)*2) ^ (u32)((row & 7) << 4);
    *(u16*)((char*)h + byte) = f2b(v);
}

__global__ __launch_bounds__(256, 2) void edge_kernel(
    const float* __restrict__ conv, const int* __restrict__ knn,
    const int* __restrict__ rowstart, const int* __restrict__ csr,
    const u16* __restrict__ wb2, const u16* __restrict__ wb3,
    float* __restrict__ xf)
{
    __shared__ float in6[6][64];
    __shared__ int   lts[64];
    __shared__ int   rs_l[17];
    __shared__ float scw1[384];
    __shared__ float sc1[64], sh1[64];
    __shared__ __align__(16) u16 h1s[64*64];    // [edge][ch]  swizzled
    __shared__ __align__(16) u16 h2s[64*128];   // [edge][ch]  swizzled
    __shared__ __align__(16) u16 h3s[64*256];   // [edge][ch]  swizzled

    const float* posf = conv + O_POS;
    const float* cb1 = conv + O_CB1; const float* cg1 = conv + O_CG1; const float* cs1 = conv + O_CS1;

    const int tid = threadIdx.x;
    const int w   = tid >> 6;          // wave id
    const int l   = tid & 63;          // lane
    const int t0  = blockIdx.x << 4;   // first of 16 targets
    const int b   = t0 >> 12;

    if (tid < 64){ float g1 = cg1[tid]; sc1[tid]=g1; sh1[tid]=cb1[tid]*g1 + cs1[tid]; }
    if (tid < 17) rs_l[tid] = rowstart[t0 + tid];
    for (int u = tid; u < 384; u += 256) scw1[u] = conv[O_CW1 + u];

    // ---- per-wave weight fragments in registers (believed k-map: k = (l>>4)*8 + i,
    //      applied identically to A and B => permutation-safe) ----
    const int lr = l & 15, lg = l >> 4;
    const int colb2 = w << 5;          // layer-2 cols [w*32, +32)
    const int colb3 = w << 6;          // layer-3 cols [w*64, +64)
    bf16x8 wf2[2][2];                  // [nt][ks]
    #pragma unroll
    for (int nt = 0; nt < 2; ++nt)
        #pragma unroll
        for (int ks = 0; ks < 2; ++ks)
            #pragma unroll
            for (int i = 0; i < 8; ++i)
                wf2[nt][ks][i] = (short)wb2[(ks*32 + lg*8 + i)*128 + colb2 + nt*16 + lr];
    bf16x8 wf3[4][4];                  // [nt][ks]
    #pragma unroll
    for (int nt = 0; nt < 4; ++nt)
        #pragma unroll
        for (int ks = 0; ks < 4; ++ks)
            #pragma unroll
            for (int i = 0; i < 8; ++i)
                wf3[nt][ks][i] = (short)wb3[(ks*32 + lg*8 + i)*256 + colb3 + nt*16 + lr];

    float sc2v[2], sh2v[2], bs3v[4];
    #pragma unroll
    for (int nt = 0; nt < 2; ++nt){
        int c = colb2 + nt*16 + lr;
        float g2 = conv[O_CG2 + c];
        sc2v[nt] = g2; sh2v[nt] = conv[O_CB2 + c]*g2 + conv[O_CS2 + c];
    }
    #pragma unroll
    for (int nt = 0; nt < 4; ++nt) bs3v[nt] = conv[O_CB3 + colb3 + nt*16 + lr];

    __syncthreads();
    const int segstart = rs_l[0], segend = rs_l[16];
    const int nchunk = (segend - segstart + 63) >> 6;

    const int c = tid;                 // reduction channel
    float xr[16];
    #pragma unroll
    for (int q = 0; q < 16; ++q) xr[q] = -3.0e38f;
    int curl = -1; float run = 0.f;

    for (int ch = 0; ch < nchunk; ++ch){
        __syncthreads();   // prev chunk fully consumed
        if (tid < 64){
            int gpos = segstart + (ch << 6) + tid;
            int lt = -1;
            float ax=0,ay=0,az=0,dx=0,dy=0,dz=0;
            if (gpos < segend){
                lt = 0;
                #pragma unroll
                for (int q = 1; q < 16; ++q) lt += (gpos >= rs_l[q]) ? 1 : 0;
                int e = csr[gpos];
                int i = (e >> 4) & (NN - 1);
                int j = knn[e];
                const float* pi = posf + ((size_t)(b*NN + i))*3;
                const float* pj = posf + ((size_t)(b*NN + j))*3;
                ax = pi[0]; ay = pi[1]; az = pi[2];
                dx = ax - pj[0]; dy = ay - pj[1]; dz = az - pj[2];
            }
            lts[tid] = lt;
            in6[0][tid]=ax; in6[1][tid]=ay; in6[2][tid]=az;
            in6[3][tid]=dx; in6[4][tid]=dy; in6[5][tid]=dz;
        }
        __syncthreads();

        { // layer 1 (VALU, K=6): thread -> edge tid&63, channels (tid>>6)*16..+15
            const int e = tid & 63, c0g = (tid >> 6) << 4;
            float a0=in6[0][e], a1=in6[1][e], a2=in6[2][e],
                  a3=in6[3][e], a4=in6[4][e], a5=in6[5][e];
            u32 pk[8];
            #pragma unroll
            for (int ci = 0; ci < 16; ++ci){
                int cc = c0g + ci;
                float acc = a0*scw1[cc]     + a1*scw1[64+cc]  + a2*scw1[128+cc]
                          + a3*scw1[192+cc] + a4*scw1[256+cc] + a5*scw1[320+cc];
                float v = fmaxf(acc*sc1[cc] + sh1[cc], 0.f);
                u32 h = (u32)f2b(v);
                if (ci & 1) pk[ci >> 1] |= h << 16; else pk[ci >> 1] = h;
            }
            u32 base = (u32)(e*128 + c0g*2);
            u32 swz  = (u32)((e & 7) << 4);
            *(uint4*)((char*)h1s + (base ^ swz))        = make_uint4(pk[0],pk[1],pk[2],pk[3]);
            *(uint4*)((char*)h1s + ((base + 16) ^ swz)) = make_uint4(pk[4],pk[5],pk[6],pk[7]);
        }
        __syncthreads();

        { // layer 2 (MFMA): M=64 edges, N=128 (wave owns 32 cols), K=64
            f32x4 acc2[4][2];
            #pragma unroll
            for (int mt = 0; mt < 4; ++mt)
                #pragma unroll
                for (int nt = 0; nt < 2; ++nt) acc2[mt][nt] = (f32x4){0.f,0.f,0.f,0.f};
            #pragma unroll
            for (int mt = 0; mt < 4; ++mt)
                #pragma unroll
                for (int ks = 0; ks < 2; ++ks){
                    bf16x8 a = ldfrag(h1s, mt*16 + lr, ks*32 + lg*8, 64);
                    #pragma unroll
                    for (int nt = 0; nt < 2; ++nt)
                        acc2[mt][nt] = __builtin_amdgcn_mfma_f32_16x16x32_bf16(a, wf2[nt][ks], acc2[mt][nt], 0, 0, 0);
                }
            #pragma unroll
            for (int mt = 0; mt < 4; ++mt)
                #pragma unroll
                for (int nt = 0; nt < 2; ++nt)
                    #pragma unroll
                    for (int r = 0; r < 4; ++r){
                        int row = mt*16 + lg*4 + r;
                        float v = fmaxf(acc2[mt][nt][r]*sc2v[nt] + sh2v[nt], 0.f);
                        st16(h2s, row, colb2 + nt*16 + lr, 128, v);
                    }
        }
        __syncthreads();

        { // layer 3 (MFMA): M=64, N=256 (wave owns 64 cols), K=128; +bias -> h3s
            f32x4 acc3[4][4];
            #pragma unroll
            for (int mt = 0; mt < 4; ++mt)
                #pragma unroll
                for (int nt = 0; nt < 4; ++nt) acc3[mt][nt] = (f32x4){0.f,0.f,0.f,0.f};
            #pragma unroll
            for (int mt = 0; mt < 4; ++mt)
                #pragma unroll
                for (int ks = 0; ks < 4; ++ks){
                    bf16x8 a = ldfrag(h2s, mt*16 + lr, ks*32 + lg*8, 128);
                    #pragma unroll
                    for (int nt = 0; nt < 4; ++nt)
                        acc3[mt][nt] = __builtin_amdgcn_mfma_f32_16x16x32_bf16(a, wf3[nt][ks], acc3[mt][nt], 0, 0, 0);
                }
            #pragma unroll
            for (int mt = 0; mt < 4; ++mt)
                #pragma unroll
                for (int nt = 0; nt < 4; ++nt)
                    #pragma unroll
                    for (int r = 0; r < 4; ++r){
                        int row = mt*16 + lg*4 + r;
                        st16(h3s, row, colb3 + nt*16 + lr, 256, acc3[mt][nt][r] + bs3v[nt]);
                    }
        }
        __syncthreads();

        // segmented max over this chunk: thread owns channel c; branch is wave-uniform
        for (int pos = 0; pos < 64; ++pos){
            int lt = lts[pos];
            u32 byte = (u32)((pos*256 + c)*2) ^ (u32)((pos & 7) << 4);
            float v = b2f(*(const u16*)((const char*)h3s + byte));
            if (lt != curl){
                if (curl >= 0){
                    #pragma unroll
                    for (int q = 0; q < 16; ++q) if (q == curl) xr[q] = fmaxf(xr[q], run);
                }
                curl = lt; run = v;
            } else {
                run = fmaxf(run, v);
            }
        }
    }
    if (curl >= 0){
        #pragma unroll
        for (int q = 0; q < 16; ++q) if (q == curl) xr[q] = fmaxf(xr[q], run);
    }
    #pragma unroll
    for (int q = 0; q < 16; ++q) xf[((size_t)(t0+q))*256 + c] = xr[q];
}

// ---------------------------------------------------------------- GlobalSA MLP + scene max
#define SAS 36
__global__ __launch_bounds__(256) void sa_kernel(
    const float* __restrict__ conv, const float* __restrict__ xf,
    u32* __restrict__ scene_map)
{
    __shared__ __align__(16) char smem[61440];
    u16* h1p = (u16*)smem;                 // [256][36] bf16; reused as f32 sred in s3
    u16* a0p = (u16*)(smem + 18432);       // [259][36] bf16
    u16* h2p = (u16*)(smem + 18432);       // [512][36] bf16 (reuses a0)
    float* sc1 = (float*)(smem + 55296);
    float* sh1 = sc1 + 256;
    float* sc2 = sh1 + 256;
    float* sh2 = sc2 + 512;

    const float* posf = conv + O_POS;
    const float* sw1 = conv + O_SW1; const float* sb1 = conv + O_SB1;
    const float* sg1 = conv + O_SG1; const float* ss1 = conv + O_SS1;
    const float* sw2 = conv + O_SW2; const float* sb2 = conv + O_SB2;
    const float* sg2 = conv + O_SG2; const float* ss2 = conv + O_SS2;
    const float* sw3 = conv + O_SW3; const float* sb3 = conv + O_SB3;

    const int tid = threadIdx.x;
    const int b  = blockIdx.x >> 7;
    const int n0 = (blockIdx.x & 127) << 5;

    for (int u = tid; u < 32*256; u += 256){
        int p = u >> 8, cc = u & 255;
        float f = xf[(((size_t)(b*NN + n0 + p)) << 8) + cc];
        a0p[cc*SAS + p] = f2b(f);
    }
    if (tid < 96){
        int p = tid & 31, cc = tid >> 5;
        a0p[(256+cc)*SAS + p] = f2b(posf[((size_t)(b*NN + n0 + p))*3 + cc]);
    }
    if (tid < 256){ float g = sg1[tid]; sc1[tid]=g; sh1[tid]=sb1[tid]*g + ss1[tid]; }
    for (int u = tid; u < 512; u += 256){ float g=sg2[u]; sc2[u]=g; sh2[u]=sb2[u]*g + ss2[u]; }
    __syncthreads();

    { // s1: 259 -> 256
        const int p0 = (tid & 7) << 2, c0 = (tid >> 3) << 3;
        float acc[8][4];
        #pragma unroll
        for (int cc=0;cc<8;++cc){
            #pragma unroll
            for (int ee=0;ee<4;++ee) acc[cc][ee]=0.f;
        }
        for (int r = 0; r < 259; ++r){
            ushort4 av = *(const ushort4*)&a0p[r*SAS + p0];
            float a[4] = { b2f(av.x), b2f(av.y), b2f(av.z), b2f(av.w) };
            float4 wa = *(const float4*)(sw1 + r*256 + c0);
            float4 wb = *(const float4*)(sw1 + r*256 + c0 + 4);
            float w[8] = {wa.x,wa.y,wa.z,wa.w, wb.x,wb.y,wb.z,wb.w};
            #pragma unroll
            for (int cc=0;cc<8;++cc){
                #pragma unroll
                for (int ee=0;ee<4;++ee) acc[cc][ee] += w[cc]*a[ee];
            }
        }
        #pragma unroll
        for (int cc=0;cc<8;++cc){
            int cg = c0 + cc;
            float s = sc1[cg], h = sh1[cg];
            ushort4 o;
            o.x=f2b(fmaxf(acc[cc][0]*s+h,0.f)); o.y=f2b(fmaxf(acc[cc][1]*s+h,0.f));
            o.z=f2b(fmaxf(acc[cc][2]*s+h,0.f)); o.w=f2b(fmaxf(acc[cc][3]*s+h,0.f));
            *(ushort4*)&h1p[cg*SAS + p0] = o;
        }
    }
    __syncthreads();

    { // s2: 256 -> 512
        const int p0 = (tid & 7) << 2, c0 = (tid >> 3) << 4;
        float acc[16][4];
        #pragma unroll
        for (int cc=0;cc<16;++cc){
            #pragma unroll
            for (int ee=0;ee<4;++ee) acc[cc][ee]=0.f;
        }
        for (int r = 0; r < 256; ++r){
            ushort4 av = *(const ushort4*)&h1p[r*SAS + p0];
            float a[4] = { b2f(av.x), b2f(av.y), b2f(av.z), b2f(av.w) };
            float4 w0 = *(const float4*)(sw2 + r*512 + c0);
            float4 w1 = *(const float4*)(sw2 + r*512 + c0 + 4);
            float4 w2 = *(const float4*)(sw2 + r*512 + c0 + 8);
            float4 w3 = *(const float4*)(sw2 + r*512 + c0 + 12);
            float w[16] = {w0.x,w0.y,w0.z,w0.w, w1.x,w1.y,w1.z,w1.w,
                           w2.x,w2.y,w2.z,w2.w, w3.x,w3.y,w3.z,w3.w};
            #pragma unroll
            for (int cc=0;cc<16;++cc){
                #pragma unroll
                for (int ee=0;ee<4;++ee) acc[cc][ee] += w[cc]*a[ee];
            }
        }
        #pragma unroll
        for (int cc=0;cc<16;++cc){
            int cg = c0 + cc;
            float s = sc2[cg], h = sh2[cg];
            ushort4 o;
            o.x=f2b(fmaxf(acc[cc][0]*s+h,0.f)); o.y=f2b(fmaxf(acc[cc][1]*s+h,0.f));
            o.z=f2b(fmaxf(acc[cc][2]*s+h,0.f)); o.w=f2b(fmaxf(acc[cc][3]*s+h,0.f));
            *(ushort4*)&h2p[cg*SAS + p0] = o;
        }
    }
    __syncthreads();

    // s3: 512 -> 1024, LDS pre-reduce, 1 atomic/channel
    for (int half = 0; half < 2; ++half){
        const int p0 = (tid & 7) << 2, c0 = (tid >> 3) << 4;
        const int cbase = (half << 9) + c0;
        float acc[16][4];
        #pragma unroll
        for (int cc=0;cc<16;++cc){
            #pragma unroll
            for (int ee=0;ee<4;++ee) acc[cc][ee]=0.f;
        }
        for (int r = 0; r < 512; ++r){
            ushort4 av = *(const ushort4*)&h2p[r*SAS + p0];
            float a[4] = { b2f(av.x), b2f(av.y), b2f(av.z), b2f(av.w) };
            float4 w0 = *(const float4*)(sw3 + r*1024 + cbase);
            float4 w1 = *(const float4*)(sw3 + r*1024 + cbase + 4);
            float4 w2 = *(const float4*)(sw3 + r*1024 + cbase + 8);
            float4 w3 = *(const float4*)(sw3 + r*1024 + cbase + 12);
            float w[16] = {w0.x,w0.y,w0.z,w0.w, w1.x,w1.y,w1.z,w1.w,
                           w2.x,w2.y,w2.z,w2.w, w3.x,w3.y,w3.z,w3.w};
            #pragma unroll
            for (int cc=0;cc<16;++cc){
                #pragma unroll
                for (int ee=0;ee<4;++ee) acc[cc][ee] += w[cc]*a[ee];
            }
        }
        float* sred = (float*)smem;   // [8][512] f32 (h1p region, dead now)
        #pragma unroll
        for (int cc=0;cc<16;++cc){
            float v = fmaxf(fmaxf(acc[cc][0], acc[cc][1]), fmaxf(acc[cc][2], acc[cc][3]));
            sred[(tid & 7)*512 + c0 + cc] = v;
        }
        __syncthreads();
        for (int ci = tid; ci < 512; ci += 256){
            float m = sred[ci];
            #pragma unroll
            for (int r = 1; r < 8; ++r) m = fmaxf(m, sred[r*512 + ci]);
            float v = m + sb3[(half << 9) + ci];
            atomicMax(scene_map + (b << 10) + (half << 9) + ci, fmap(v));
        }
        __syncthreads();
    }
}

// ---------------------------------------------------------------- head
__global__ __launch_bounds__(128) void head1_kernel(
    const float* __restrict__ conv,
    const float* __restrict__ xf, const u32* __restrict__ scene_map, const int* __restrict__ qidx,
    float* __restrict__ h1out)
{
    __shared__ float ef[1280];
    const float* pw1 = conv + O_PW1; const float* pb1 = conv + O_PB1;
    const int b  = blockIdx.x >> 2;
    const int c0 = (blockIdx.x & 3) << 7;
    const int tid = threadIdx.x;
    const int q = qidx[b];
    for (int u = tid; u < 1280; u += 128){
        float v;
        if (u < 256) v = xf[(((size_t)(b*NN + q)) << 8) + u];
        else         v = funmap(scene_map[(b << 10) + (u - 256)]);
        ef[u] = v;
    }
    __syncthreads();
    const int c = c0 + tid;
    float acc = pb1[c];
    for (int r = 0; r < 1280; ++r) acc += ef[r] * pw1[r*512 + c];
    h1out[(b << 9) + c] = fmaxf(acc, 0.f);
}

__global__ __launch_bounds__(256) void head2_kernel(
    const float* __restrict__ conv, const float* __restrict__ h1in,
    const u32* __restrict__ flagp, void* __restrict__ outv)
{
    __shared__ float h1[4][512];
    __shared__ float h2[4][256];
    const float* pw2 = conv + O_PW2; const float* pb2 = conv + O_PB2;
    const float* pw3 = conv + O_PW3; const float* pb3 = conv + O_PB3;
    const int tid = threadIdx.x;
    for (int u = tid; u < 2048; u += 256) h1[u >> 9][u & 511] = h1in[u];
    __syncthreads();
    for (int o = tid; o < 1024; o += 256){
        int b = o >> 8, c = o & 255;
        float acc = pb2[c];
        for (int r = 0; r < 512; ++r) acc += h1[b][r] * pw2[r*256 + c];
        h2[b][c] = fmaxf(acc, 0.f);
    }
    __syncthreads();
    if (tid < 64){
        int b = tid >> 4, c = tid & 15;
        float acc = pb3[c];
        for (int r = 0; r < 256; ++r) acc += h2[b][r] * pw3[r*16 + c];
        if (*flagp) ((u16*)outv)[tid] = f2b(acc);
        else        ((float*)outv)[tid] = acc;
    }
}

// ---------------------------------------------------------------- launch
extern "C" void kernel_launch(void* const* d_in, const int* in_sizes, int n_in,
                              void* d_out, int out_size, void* d_ws, size_t ws_size,
                              hipStream_t stream){
    (void)in_sizes; (void)n_in; (void)out_size; (void)ws_size;
    const int* qidx = (const int*)d_in[1];

    char* ws = (char*)d_ws;
    u32*  flag      = (u32*)ws;                       // @0
    float* conv     = (float*)(ws + 1024);            // 6.43 MB f32 (ends 6431552)
    u16*  wb2       = (u16*)(ws + 6432768);           // 16 KB bf16 cw2
    u16*  wb3       = (u16*)(ws + 6449152);           // 64 KB bf16 cw3
    int*  knn       = (int*)(ws + 6553600);           // 1 MB
    u32*  deg       = (u32*)(ws + 7602176);           // 64 KB
    u32*  scene_map = (u32*)(ws + 7667712);           // 16 KB
    int*  rowstart  = (int*)(ws + 7684096);           // 64 KB + 4
    u32*  cursor    = (u32*)(ws + 7749760);           // 64 KB
    int*  csr       = (int*)(ws + 7815296);           // 1 MB
    float* xf       = (float*)(ws + 8863872);         // 16 MB  [B*N, 256] f32
    float* h1ws     = (float*)(ws + 25641088);        // 8 KB

    Ptrs pt;
    pt.p[0] = d_in[0];
    for (int k = 1; k < N_ARR; ++k) pt.p[k] = d_in[k + 1];

    hipMemsetAsync(ws + 7602176, 0, 81920, stream);   // deg + scene_map

    detect_kernel <<<1, 256, 0, stream>>>((const u16*)d_in[0], flag);
    convert_kernel<<<512, 256, 0, stream>>>(pt, flag, conv);
    wconv_kernel  <<<64, 256, 0, stream>>>(conv, wb2, wb3);
    knn_kernel <<<4096, 256, 0, stream>>>(conv, knn);
    cnt_kernel <<<1024, 256, 0, stream>>>(knn, deg);
    scan_kernel<<<1, 1024, 0, stream>>>(deg, rowstart, cursor);
    fill_kernel<<<1024, 256, 0, stream>>>(knn, cursor, csr);
    edge_kernel<<<1024, 256, 0, stream>>>(conv, knn, rowstart, csr, wb2, wb3, xf);
    sa_kernel  <<<512, 256, 0, stream>>>(conv, xf, scene_map);
    head1_kernel<<<16, 128, 0, stream>>>(conv, xf, scene_map, qidx, h1ws);
    head2_kernel<<<1, 256, 0, stream>>>(conv, h1ws, flag, (void*)d_out);
}

// Round 5
// 616.737 us; speedup vs baseline: 7.2864x; 1.4625x over previous
//
#include <hip/hip_runtime.h>

#define BB 4
#define NN 4096
#define KK 16

typedef unsigned short u16;
typedef unsigned int   u32;
typedef unsigned long long u64;

typedef __attribute__((ext_vector_type(8))) short bf16x8;
typedef __attribute__((ext_vector_type(4))) float f32x4;

__device__ __forceinline__ float b2f(u16 x){ return __uint_as_float(((u32)x) << 16); }
__device__ __forceinline__ u16 f2b(float f){
    u32 u = __float_as_uint(f);
    u32 r = (u + 0x7FFFu + ((u >> 16) & 1u)) >> 16;   // RNE
    return (u16)r;
}
__device__ __forceinline__ u32 fmap(float f){
    u32 u = __float_as_uint(f);
    return (u & 0x80000000u) ? ~u : (u | 0x80000000u);
}
__device__ __forceinline__ float funmap(u32 u){
    u32 v = (u & 0x80000000u) ? (u ^ 0x80000000u) : ~u;
    return __uint_as_float(v);
}

// ---------------- input normalization (runtime dtype detect: f32 vs bf16) ----
#define N_ARR 27
__device__ const int ASZ[N_ARR] = {
    49152, 384, 64, 64, 64, 8192, 128, 128, 128, 32768, 256,
    66304, 256, 256, 256, 131072, 512, 512, 512, 524288, 1024,
    655360, 512, 131072, 256, 4096, 16 };
__device__ const int AOFF[N_ARR] = {
    0, 49152, 49536, 49600, 49664, 49728, 57920, 58048, 58176, 58304, 91072,
    91328, 157632, 157888, 158144, 158400, 289472, 289984, 290496, 291008, 815296,
    816320, 1471680, 1472192, 1603264, 1603520, 1607616 };

struct Ptrs { const void* p[N_ARR]; };

#define O_POS 0
#define O_CW1 49152
#define O_CB1 49536
#define O_CG1 49600
#define O_CS1 49664
#define O_CW2 49728
#define O_CB2 57920
#define O_CG2 58048
#define O_CS2 58176
#define O_CW3 58304
#define O_CB3 91072
#define O_SW1 91328
#define O_SB1 157632
#define O_SG1 157888
#define O_SS1 158144
#define O_SW2 158400
#define O_SB2 289472
#define O_SG2 289984
#define O_SS2 290496
#define O_SW3 291008
#define O_SB3 815296
#define O_PW1 816320
#define O_PB1 1471680
#define O_PW2 1472192
#define O_PB2 1603264
#define O_PW3 1603520
#define O_PB3 1607616

__global__ void detect_kernel(const u16* __restrict__ pos_u16, u32* __restrict__ flag){
    __shared__ int cnt;
    if (threadIdx.x == 0) cnt = 0;
    __syncthreads();
    int c = 0;
    #pragma unroll
    for (int s = 0; s < 4; ++s){
        u16 u = pos_u16[2*(threadIdx.x*4 + s)];
        int e = (u >> 7) & 0xFF;
        c += (e >= 0x68 && e <= 0x82) ? 1 : 0;
    }
    atomicAdd(&cnt, c);
    __syncthreads();
    if (threadIdx.x == 0) *flag = (cnt >= 512) ? 1u : 0u;   // 1 = bf16 inputs
}

__global__ __launch_bounds__(256) void convert_kernel(Ptrs pt, const u32* __restrict__ flagp,
                                                      float* __restrict__ dst){
    const bool isbf = (*flagp != 0);
    const int T = gridDim.x * 256;
    const int g = blockIdx.x * 256 + threadIdx.x;
    #pragma unroll
    for (int a = 0; a < N_ARR; ++a){
        const int sz = ASZ[a], off = AOFF[a];
        if (isbf){
            const u16* s = (const u16*)pt.p[a];
            for (int i = g; i < sz; i += T) dst[off + i] = b2f(s[i]);
        } else {
            const float* s = (const float*)pt.p[a];
            for (int i = g; i < sz; i += T) dst[off + i] = s[i];
        }
    }
}

// Pack weight matrix (row-major KxN f32) into MFMA B-fragment order:
// dst[((ks*N + n)*4 + lg)*8 + i] = bf16(W[(ks*32 + lg*8 + i)*N + n])
__device__ __forceinline__ void pack_one(const float* __restrict__ src, u16* __restrict__ dst,
                                         int tot, int log2n, int g, int T){
    const int nmask = (1 << log2n) - 1;
    for (int id = g; id < tot; id += T){
        int i = id & 7, lg = (id >> 3) & 3;
        int rest = id >> 5;
        int n = rest & nmask;
        int ks = rest >> log2n;
        dst[id] = f2b(src[(ks*32 + lg*8 + i) << log2n | n]);
    }
}

__global__ __launch_bounds__(256) void wpack_kernel(const float* __restrict__ conv,
        u16* __restrict__ wp2, u16* __restrict__ wp3,
        u16* __restrict__ swp1, u16* __restrict__ swp2, u16* __restrict__ swp3){
    const int T = gridDim.x * 256;
    const int g = blockIdx.x * 256 + threadIdx.x;
    pack_one(conv + O_CW2, wp2,   8192, 7, g, T);
    pack_one(conv + O_CW3, wp3,  32768, 8, g, T);
    pack_one(conv + O_SW1, swp1, 65536, 8, g, T);   // first 256 K-rows only
    pack_one(conv + O_SW2, swp2, 131072, 9, g, T);
    pack_one(conv + O_SW3, swp3, 524288, 10, g, T);
}

// ---------------------------------------------------------------- kNN
__global__ __launch_bounds__(256) void knn_kernel(const float* __restrict__ conv,
                                                  int* __restrict__ knn_out){
    __shared__ float sx[NN], sy[NN], sz[NN];
    const float* posf = conv + O_POS;
    const int b  = blockIdx.x >> 10;
    const int i0 = (blockIdx.x & 1023) << 2;
    const int tid = threadIdx.x;
    for (int t = tid; t < NN; t += 256){
        const float* p = posf + ((size_t)(b*NN + t))*3;
        sx[t] = p[0]; sy[t] = p[1]; sz[t] = p[2];
    }
    __syncthreads();
    const int lane = tid & 63;
    const int i = i0 + (tid >> 6);
    const float pix = sx[i], piy = sy[i], piz = sz[i];

    float d[KK]; int id[KK];
    #pragma unroll
    for (int t = 0; t < KK; ++t){
        int j = lane + (t << 6);
        float dx = pix - sx[j], dy = piy - sy[j], dz = piz - sz[j];
        d[t] = __fadd_rn(__fadd_rn(__fmul_rn(dx,dx), __fmul_rn(dy,dy)), __fmul_rn(dz,dz));
        id[t] = j;
    }
    float dmax = d[0]; int amax = 0;
    #pragma unroll
    for (int p = 1; p < KK; ++p){ bool c = d[p] > dmax; dmax = c ? d[p] : dmax; amax = c ? p : amax; }

    for (int t = KK; t < 64; ++t){
        int j = lane + (t << 6);
        float dx = pix - sx[j], dy = piy - sy[j], dz = piz - sz[j];
        float d2 = __fadd_rn(__fadd_rn(__fmul_rn(dx,dx), __fmul_rn(dy,dy)), __fmul_rn(dz,dz));
        if (d2 < dmax){
            #pragma unroll
            for (int p = 0; p < KK; ++p){ bool c = (p == amax); d[p] = c ? d2 : d[p]; id[p] = c ? j : id[p]; }
            dmax = d[0]; amax = 0;
            #pragma unroll
            for (int p = 1; p < KK; ++p){ bool c = d[p] > dmax; dmax = c ? d[p] : dmax; amax = c ? p : amax; }
        }
    }
    u64 key[KK];
    #pragma unroll
    for (int p = 0; p < KK; ++p) key[p] = (((u64)__float_as_uint(d[p])) << 32) | (u32)id[p];
    int* outp = knn_out + ((size_t)(b*NN + i))*KK;
    for (int r = 0; r < KK; ++r){
        u64 m = key[0];
        #pragma unroll
        for (int p = 1; p < KK; ++p) m = key[p] < m ? key[p] : m;
        #pragma unroll
        for (int off = 32; off > 0; off >>= 1){
            u64 o = __shfl_xor(m, off);
            m = o < m ? o : m;
        }
        if (lane == 0) outp[r] = (int)(u32)(m & 0xFFFFFFFFu);
        #pragma unroll
        for (int p = 0; p < KK; ++p) if (key[p] == m) key[p] = ~0ull;
    }
}

// ---------------------------------------------------------------- CSR build
__global__ __launch_bounds__(256) void cnt_kernel(const int* __restrict__ knn, u32* __restrict__ deg){
    int e = blockIdx.x*256 + threadIdx.x;
    int b = e >> 16;
    int t = (b << 12) + knn[e];
    atomicAdd(deg + t, 1u);
}

__global__ __launch_bounds__(1024) void scan_kernel(const u32* __restrict__ deg,
                                                    int* __restrict__ rowstart, u32* __restrict__ cursor){
    __shared__ int lsum[1024];
    const int tid = threadIdx.x;
    const int base = tid * 16;
    int loc[16]; int s = 0;
    #pragma unroll
    for (int q = 0; q < 16; ++q){ loc[q] = (int)deg[base+q]; s += loc[q]; }
    lsum[tid] = s;
    __syncthreads();
    int acc = s;
    for (int ofs = 1; ofs < 1024; ofs <<= 1){
        int t = (tid >= ofs) ? lsum[tid-ofs] : 0;
        __syncthreads();
        acc += t; lsum[tid] = acc;
        __syncthreads();
    }
    int excl = acc - s;
    #pragma unroll
    for (int q = 0; q < 16; ++q){
        rowstart[base+q] = excl; cursor[base+q] = (u32)excl; excl += loc[q];
    }
    if (tid == 1023) rowstart[16384] = excl;
}

__global__ __launch_bounds__(256) void fill_kernel(const int* __restrict__ knn,
                                                   u32* __restrict__ cursor, int* __restrict__ csr){
    int e = blockIdx.x*256 + threadIdx.x;
    int b = e >> 16;
    int t = (b << 12) + knn[e];
    u32 pos = atomicAdd(cursor + t, 1u);
    csr[pos] = e;
}

// ---------------------------------------------------------------- LDS fragment helpers
__device__ __forceinline__ bf16x8 ldfrag(const u16* h, int row, int kofs, int rowstride){
    u32 byte = (u32)((row*rowstride + kofs)*2) ^ (u32)((row & 7) << 4);
    return *(const bf16x8*)((const char*)h + byte);
}
__device__ __forceinline__ void st16(u16* h, int row, int col, int rowstride, float v){
    u32 byte = (u32)((row*rowstride + col)*2) ^ (u32)((row & 7) << 4);
    *(u16*)((char*)h + byte) = f2b(v);
}

// ---------------------------------------------------------------- edge MLP (MFMA) + segment max
__global__ __launch_bounds__(256, 2) void edge_kernel(
    const float* __restrict__ conv, const int* __restrict__ knn,
    const int* __restrict__ rowstart, const int* __restrict__ csr,
    const u16* __restrict__ wp2, const u16* __restrict__ wp3,
    u16* __restrict__ xh)
{
    __shared__ float in6[6][64];
    __shared__ int   lts[64];
    __shared__ int   rs_l[17];
    __shared__ float scw1[384];
    __shared__ float sc1[64], sh1[64];
    __shared__ __align__(16) u16 h1s[64*64];
    __shared__ __align__(16) u16 h2s[64*128];
    __shared__ __align__(16) u16 h3s[64*256];

    const float* posf = conv + O_POS;
    const float* cb1 = conv + O_CB1; const float* cg1 = conv + O_CG1; const float* cs1 = conv + O_CS1;

    const int tid = threadIdx.x;
    const int w   = tid >> 6;
    const int l   = tid & 63;
    const int t0  = blockIdx.x << 4;
    const int b   = t0 >> 12;

    if (tid < 64){ float g1 = cg1[tid]; sc1[tid]=g1; sh1[tid]=cb1[tid]*g1 + cs1[tid]; }
    if (tid < 17) rs_l[tid] = rowstart[t0 + tid];
    for (int u = tid; u < 384; u += 256) scw1[u] = conv[O_CW1 + u];

    const int lr = l & 15, lg = l >> 4;
    const int colb2 = w << 5;
    const int colb3 = w << 6;
    bf16x8 wf2[2][2];
    #pragma unroll
    for (int nt = 0; nt < 2; ++nt)
        #pragma unroll
        for (int ks = 0; ks < 2; ++ks)
            wf2[nt][ks] = *(const bf16x8*)(wp2 + (((ks*128 + colb2 + nt*16 + lr) << 2) + lg)*8);
    bf16x8 wf3[4][4];
    #pragma unroll
    for (int nt = 0; nt < 4; ++nt)
        #pragma unroll
        for (int ks = 0; ks < 4; ++ks)
            wf3[nt][ks] = *(const bf16x8*)(wp3 + (((ks*256 + colb3 + nt*16 + lr) << 2) + lg)*8);

    float sc2v[2], sh2v[2], bs3v[4];
    #pragma unroll
    for (int nt = 0; nt < 2; ++nt){
        int c = colb2 + nt*16 + lr;
        float g2 = conv[O_CG2 + c];
        sc2v[nt] = g2; sh2v[nt] = conv[O_CB2 + c]*g2 + conv[O_CS2 + c];
    }
    #pragma unroll
    for (int nt = 0; nt < 4; ++nt) bs3v[nt] = conv[O_CB3 + colb3 + nt*16 + lr];

    __syncthreads();
    const int segstart = rs_l[0], segend = rs_l[16];
    const int nchunk = (segend - segstart + 63) >> 6;

    const int c = tid;
    float xr[16];
    #pragma unroll
    for (int q = 0; q < 16; ++q) xr[q] = -3.0e38f;
    int curl = -1; float run = 0.f;

    for (int ch = 0; ch < nchunk; ++ch){
        __syncthreads();
        if (tid < 64){
            int gpos = segstart + (ch << 6) + tid;
            int lt = -1;
            float ax=0,ay=0,az=0,dx=0,dy=0,dz=0;
            if (gpos < segend){
                lt = 0;
                #pragma unroll
                for (int q = 1; q < 16; ++q) lt += (gpos >= rs_l[q]) ? 1 : 0;
                int e = csr[gpos];
                int i = (e >> 4) & (NN - 1);
                int j = knn[e];
                const float* pi = posf + ((size_t)(b*NN + i))*3;
                const float* pj = posf + ((size_t)(b*NN + j))*3;
                ax = pi[0]; ay = pi[1]; az = pi[2];
                dx = ax - pj[0]; dy = ay - pj[1]; dz = az - pj[2];
            }
            lts[tid] = lt;
            in6[0][tid]=ax; in6[1][tid]=ay; in6[2][tid]=az;
            in6[3][tid]=dx; in6[4][tid]=dy; in6[5][tid]=dz;
        }
        __syncthreads();

        { // layer 1 (VALU, K=6)
            const int e = tid & 63, c0g = (tid >> 6) << 4;
            float a0=in6[0][e], a1=in6[1][e], a2=in6[2][e],
                  a3=in6[3][e], a4=in6[4][e], a5=in6[5][e];
            u32 pk[8];
            #pragma unroll
            for (int ci = 0; ci < 16; ++ci){
                int cc = c0g + ci;
                float acc = a0*scw1[cc]     + a1*scw1[64+cc]  + a2*scw1[128+cc]
                          + a3*scw1[192+cc] + a4*scw1[256+cc] + a5*scw1[320+cc];
                float v = fmaxf(acc*sc1[cc] + sh1[cc], 0.f);
                u32 h = (u32)f2b(v);
                if (ci & 1) pk[ci >> 1] |= h << 16; else pk[ci >> 1] = h;
            }
            u32 base = (u32)(e*128 + c0g*2);
            u32 swz  = (u32)((e & 7) << 4);
            *(uint4*)((char*)h1s + (base ^ swz))        = make_uint4(pk[0],pk[1],pk[2],pk[3]);
            *(uint4*)((char*)h1s + ((base + 16) ^ swz)) = make_uint4(pk[4],pk[5],pk[6],pk[7]);
        }
        __syncthreads();

        { // layer 2 (MFMA): M=64, N=128, K=64
            f32x4 acc2[4][2];
            #pragma unroll
            for (int mt = 0; mt < 4; ++mt)
                #pragma unroll
                for (int nt = 0; nt < 2; ++nt) acc2[mt][nt] = (f32x4){0.f,0.f,0.f,0.f};
            #pragma unroll
            for (int mt = 0; mt < 4; ++mt)
                #pragma unroll
                for (int ks = 0; ks < 2; ++ks){
                    bf16x8 a = ldfrag(h1s, mt*16 + lr, ks*32 + lg*8, 64);
                    #pragma unroll
                    for (int nt = 0; nt < 2; ++nt)
                        acc2[mt][nt] = __builtin_amdgcn_mfma_f32_16x16x32_bf16(a, wf2[nt][ks], acc2[mt][nt], 0, 0, 0);
                }
            #pragma unroll
            for (int mt = 0; mt < 4; ++mt)
                #pragma unroll
                for (int nt = 0; nt < 2; ++nt)
                    #pragma unroll
                    for (int r = 0; r < 4; ++r){
                        int row = mt*16 + lg*4 + r;
                        float v = fmaxf(acc2[mt][nt][r]*sc2v[nt] + sh2v[nt], 0.f);
                        st16(h2s, row, colb2 + nt*16 + lr, 128, v);
                    }
        }
        __syncthreads();

        { // layer 3 (MFMA): M=64, N=256, K=128
            f32x4 acc3[4][4];
            #pragma unroll
            for (int mt = 0; mt < 4; ++mt)
                #pragma unroll
                for (int nt = 0; nt < 4; ++nt) acc3[mt][nt] = (f32x4){0.f,0.f,0.f,0.f};
            #pragma unroll
            for (int mt = 0; mt < 4; ++mt)
                #pragma unroll
                for (int ks = 0; ks < 4; ++ks){
                    bf16x8 a = ldfrag(h2s, mt*16 + lr, ks*32 + lg*8, 128);
                    #pragma unroll
                    for (int nt = 0; nt < 4; ++nt)
                        acc3[mt][nt] = __builtin_amdgcn_mfma_f32_16x16x32_bf16(a, wf3[nt][ks], acc3[mt][nt], 0, 0, 0);
                }
            #pragma unroll
            for (int mt = 0; mt < 4; ++mt)
                #pragma unroll
                for (int nt = 0; nt < 4; ++nt)
                    #pragma unroll
                    for (int r = 0; r < 4; ++r){
                        int row = mt*16 + lg*4 + r;
                        st16(h3s, row, colb3 + nt*16 + lr, 256, acc3[mt][nt][r] + bs3v[nt]);
                    }
        }
        __syncthreads();

        for (int pos = 0; pos < 64; ++pos){
            int lt = lts[pos];
            u32 byte = (u32)((pos*256 + c)*2) ^ (u32)((pos & 7) << 4);
            float v = b2f(*(const u16*)((const char*)h3s + byte));
            if (lt != curl){
                if (curl >= 0){
                    #pragma unroll
                    for (int q = 0; q < 16; ++q) if (q == curl) xr[q] = fmaxf(xr[q], run);
                }
                curl = lt; run = v;
            } else {
                run = fmaxf(run, v);
            }
        }
    }
    if (curl >= 0){
        #pragma unroll
        for (int q = 0; q < 16; ++q) if (q == curl) xr[q] = fmaxf(xr[q], run);
    }
    #pragma unroll
    for (int q = 0; q < 16; ++q) xh[((size_t)(t0+q))*256 + c] = f2b(xr[q]);
}

// ---------------------------------------------------------------- GlobalSA MLP (MFMA) + scene max
// Block = 32 points, 4 waves own column strips. K=256 via MFMA; pos rank-3 update in acc init.
__global__ __launch_bounds__(256, 2) void sa_kernel(
    const float* __restrict__ conv, const u16* __restrict__ xh,
    const u16* __restrict__ swp1, const u16* __restrict__ swp2, const u16* __restrict__ swp3,
    u32* __restrict__ scene_map)
{
    __shared__ __align__(16) u16 a0s[32*256];   // 16KB swizzled [pt][ch]
    __shared__ __align__(16) u16 h1s[32*256];   // 16KB
    __shared__ __align__(16) u16 h2s[32*512];   // 32KB
    __shared__ float spw[3][256];
    __shared__ float spx[32], spy[32], spz[32];

    const int tid = threadIdx.x;
    const int w   = tid >> 6;
    const int l   = tid & 63;
    const int lr  = l & 15, lg = l >> 4;
    const int b   = blockIdx.x >> 7;
    const int n0  = (blockIdx.x & 127) << 5;

    // stage x (bf16) into swizzled LDS
    #pragma unroll
    for (int it = 0; it < 4; ++it){
        int slot = it*256 + tid;            // 1024 slots of 16B
        int row = slot >> 5, ch0 = (slot & 31) << 3;
        uint4 v = *(const uint4*)(xh + ((size_t)(b*NN + n0 + row))*256 + ch0);
        *(uint4*)((char*)a0s + ((u32)(row*512 + ch0*2) ^ (u32)((row & 7) << 4))) = v;
    }
    if (tid < 96){
        int p = tid & 31, d = tid >> 5;
        float v = conv[O_POS + ((size_t)(b*NN + n0 + p))*3 + d];
        if (d == 0) spx[p] = v; else if (d == 1) spy[p] = v; else spz[p] = v;
    }
    for (int u = tid; u < 768; u += 256)
        spw[u >> 8][u & 255] = conv[O_SW1 + (256 + (u >> 8))*256 + (u & 255)];
    __syncthreads();

    { // s1: [32x256] @ sw1[0:256] + pos @ sw1[256:259] ; N=256, wave cols [w*64, +64)
        const int c0 = w << 6;
        float sc1v[4], sh1v[4];
        #pragma unroll
        for (int nt = 0; nt < 4; ++nt){
            int cc = c0 + nt*16 + lr;
            float g = conv[O_SG1 + cc];
            sc1v[nt] = g; sh1v[nt] = conv[O_SB1 + cc]*g + conv[O_SS1 + cc];
        }
        f32x4 acc[2][4];
        #pragma unroll
        for (int mt = 0; mt < 2; ++mt)
            #pragma unroll
            for (int nt = 0; nt < 4; ++nt)
                #pragma unroll
                for (int r = 0; r < 4; ++r){
                    int row = mt*16 + lg*4 + r;
                    int cc  = c0 + nt*16 + lr;
                    acc[mt][nt][r] = spx[row]*spw[0][cc] + spy[row]*spw[1][cc] + spz[row]*spw[2][cc];
                }
        #pragma unroll
        for (int ks = 0; ks < 8; ++ks){
            bf16x8 bf[4];
            #pragma unroll
            for (int nt = 0; nt < 4; ++nt)
                bf[nt] = *(const bf16x8*)(swp1 + (((ks*256 + c0 + nt*16 + lr) << 2) + lg)*8);
            #pragma unroll
            for (int mt = 0; mt < 2; ++mt){
                bf16x8 a = ldfrag(a0s, mt*16 + lr, ks*32 + lg*8, 256);
                #pragma unroll
                for (int nt = 0; nt < 4; ++nt)
                    acc[mt][nt] = __builtin_amdgcn_mfma_f32_16x16x32_bf16(a, bf[nt], acc[mt][nt], 0, 0, 0);
            }
        }
        #pragma unroll
        for (int mt = 0; mt < 2; ++mt)
            #pragma unroll
            for (int nt = 0; nt < 4; ++nt)
                #pragma unroll
                for (int r = 0; r < 4; ++r){
                    int row = mt*16 + lg*4 + r;
                    float v = fmaxf(acc[mt][nt][r]*sc1v[nt] + sh1v[nt], 0.f);
                    st16(h1s, row, c0 + nt*16 + lr, 256, v);
                }
    }
    __syncthreads();

    { // s2: 256 -> 512 ; wave cols [w*128, +128)
        const int c0 = w << 7;
        float sc2v[8], sh2v[8];
        #pragma unroll
        for (int nt = 0; nt < 8; ++nt){
            int cc = c0 + nt*16 + lr;
            float g = conv[O_SG2 + cc];
            sc2v[nt] = g; sh2v[nt] = conv[O_SB2 + cc]*g + conv[O_SS2 + cc];
        }
        f32x4 acc[2][8];
        #pragma unroll
        for (int mt = 0; mt < 2; ++mt)
            #pragma unroll
            for (int nt = 0; nt < 8; ++nt) acc[mt][nt] = (f32x4){0.f,0.f,0.f,0.f};
        #pragma unroll
        for (int ks = 0; ks < 8; ++ks){
            bf16x8 bf[8];
            #pragma unroll
            for (int nt = 0; nt < 8; ++nt)
                bf[nt] = *(const bf16x8*)(swp2 + (((ks*512 + c0 + nt*16 + lr) << 2) + lg)*8);
            #pragma unroll
            for (int mt = 0; mt < 2; ++mt){
                bf16x8 a = ldfrag(h1s, mt*16 + lr, ks*32 + lg*8, 256);
                #pragma unroll
                for (int nt = 0; nt < 8; ++nt)
                    acc[mt][nt] = __builtin_amdgcn_mfma_f32_16x16x32_bf16(a, bf[nt], acc[mt][nt], 0, 0, 0);
            }
        }
        #pragma unroll
        for (int mt = 0; mt < 2; ++mt)
            #pragma unroll
            for (int nt = 0; nt < 8; ++nt)
                #pragma unroll
                for (int r = 0; r < 4; ++r){
                    int row = mt*16 + lg*4 + r;
                    float v = fmaxf(acc[mt][nt][r]*sc2v[nt] + sh2v[nt], 0.f);
                    st16(h2s, row, c0 + nt*16 + lr, 512, v);
                }
    }
    __syncthreads();

    // s3: 512 -> 1024 in two N-halves; block max over 32 points, then atomic scene max
    #pragma unroll
    for (int half = 0; half < 2; ++half){
        const int c0 = (half << 9) + (w << 7);
        f32x4 acc[2][8];
        #pragma unroll
        for (int mt = 0; mt < 2; ++mt)
            #pragma unroll
            for (int nt = 0; nt < 8; ++nt) acc[mt][nt] = (f32x4){0.f,0.f,0.f,0.f};
        #pragma unroll
        for (int ks = 0; ks < 16; ++ks){
            bf16x8 bf[8];
            #pragma unroll
            for (int nt = 0; nt < 8; ++nt)
                bf[nt] = *(const bf16x8*)(swp3 + (((ks*1024 + c0 + nt*16 + lr) << 2) + lg)*8);
            #pragma unroll
            for (int mt = 0; mt < 2; ++mt){
                bf16x8 a = ldfrag(h2s, mt*16 + lr, ks*32 + lg*8, 512);
                #pragma unroll
                for (int nt = 0; nt < 8; ++nt)
                    acc[mt][nt] = __builtin_amdgcn_mfma_f32_16x16x32_bf16(a, bf[nt], acc[mt][nt], 0, 0, 0);
            }
        }
        #pragma unroll
        for (int nt = 0; nt < 8; ++nt){
            float v = acc[0][nt][0];
            #pragma unroll
            for (int mt = 0; mt < 2; ++mt)
                #pragma unroll
                for (int r = 0; r < 4; ++r) v = fmaxf(v, acc[mt][nt][r]);
            v = fmaxf(v, __shfl_xor(v, 16));
            v = fmaxf(v, __shfl_xor(v, 32));
            if (lg == 0){
                int cc = c0 + nt*16 + lr;
                atomicMax(scene_map + (b << 10) + cc, fmap(v + conv[O_SB3 + cc]));
            }
        }
    }
}

// ---------------------------------------------------------------- head
__global__ __launch_bounds__(128) void head1_kernel(
    const float* __restrict__ conv,
    const u16* __restrict__ xh, const u32* __restrict__ scene_map, const int* __restrict__ qidx,
    float* __restrict__ h1out)
{
    __shared__ float ef[1280];
    const float* pw1 = conv + O_PW1; const float* pb1 = conv + O_PB1;
    const int b  = blockIdx.x >> 2;
    const int c0 = (blockIdx.x & 3) << 7;
    const int tid = threadIdx.x;
    const int q = qidx[b];
    for (int u = tid; u < 1280; u += 128){
        float v;
        if (u < 256) v = b2f(xh[(((size_t)(b*NN + q)) << 8) + u]);
        else         v = funmap(scene_map[(b << 10) + (u - 256)]);
        ef[u] = v;
    }
    __syncthreads();
    const int c = c0 + tid;
    float acc = pb1[c];
    for (int r = 0; r < 1280; ++r) acc += ef[r] * pw1[r*512 + c];
    h1out[(b << 9) + c] = fmaxf(acc, 0.f);
}

__global__ __launch_bounds__(256) void head2_kernel(
    const float* __restrict__ conv, const float* __restrict__ h1in,
    const u32* __restrict__ flagp, void* __restrict__ outv)
{
    __shared__ float h1[4][512];
    __shared__ float h2[4][256];
    const float* pw2 = conv + O_PW2; const float* pb2 = conv + O_PB2;
    const float* pw3 = conv + O_PW3; const float* pb3 = conv + O_PB3;
    const int tid = threadIdx.x;
    for (int u = tid; u < 2048; u += 256) h1[u >> 9][u & 511] = h1in[u];
    __syncthreads();
    for (int o = tid; o < 1024; o += 256){
        int b = o >> 8, c = o & 255;
        float acc = pb2[c];
        for (int r = 0; r < 512; ++r) acc += h1[b][r] * pw2[r*256 + c];
        h2[b][c] = fmaxf(acc, 0.f);
    }
    __syncthreads();
    if (tid < 64){
        int b = tid >> 4, c = tid & 15;
        float acc = pb3[c];
        for (int r = 0; r < 256; ++r) acc += h2[b][r] * pw3[r*16 + c];
        if (*flagp) ((u16*)outv)[tid] = f2b(acc);
        else        ((float*)outv)[tid] = acc;
    }
}

// ---------------------------------------------------------------- launch
extern "C" void kernel_launch(void* const* d_in, const int* in_sizes, int n_in,
                              void* d_out, int out_size, void* d_ws, size_t ws_size,
                              hipStream_t stream){
    (void)in_sizes; (void)n_in; (void)out_size; (void)ws_size;
    const int* qidx = (const int*)d_in[1];

    char* ws = (char*)d_ws;
    u32*  flag      = (u32*)ws;                       // @0
    float* conv     = (float*)(ws + 1024);            // 6.43 MB f32
    u16*  wp2       = (u16*)(ws + 6432768);           // 16 KB  packed cw2
    u16*  wp3       = (u16*)(ws + 6449152);           // 64 KB  packed cw3
    u16*  swp1      = (u16*)(ws + 6514688);           // 128 KB packed sw1[0:256]
    u16*  swp2      = (u16*)(ws + 6645760);           // 256 KB packed sw2
    u16*  swp3      = (u16*)(ws + 6907904);           // 1 MB   packed sw3
    int*  knn       = (int*)(ws + 7956480);           // 1 MB
    u32*  deg       = (u32*)(ws + 9005056);           // 64 KB
    u32*  scene_map = (u32*)(ws + 9070592);           // 16 KB
    int*  rowstart  = (int*)(ws + 9086976);           // 64 KB + 4
    u32*  cursor    = (u32*)(ws + 9152576);           // 64 KB
    int*  csr       = (int*)(ws + 9218112);           // 1 MB
    u16*  xh        = (u16*)(ws + 10266688);          // 8 MB  [B*N, 256] bf16
    float* h1ws     = (float*)(ws + 18655296);        // 8 KB

    Ptrs pt;
    pt.p[0] = d_in[0];
    for (int k = 1; k < N_ARR; ++k) pt.p[k] = d_in[k + 1];

    hipMemsetAsync(ws + 9005056, 0, 81920, stream);   // deg + scene_map

    detect_kernel <<<1, 256, 0, stream>>>((const u16*)d_in[0], flag);
    convert_kernel<<<512, 256, 0, stream>>>(pt, flag, conv);
    wpack_kernel  <<<256, 256, 0, stream>>>(conv, wp2, wp3, swp1, swp2, swp3);
    knn_kernel <<<4096, 256, 0, stream>>>(conv, knn);
    cnt_kernel <<<1024, 256, 0, stream>>>(knn, deg);
    scan_kernel<<<1, 1024, 0, stream>>>(deg, rowstart, cursor);
    fill_kernel<<<1024, 256, 0, stream>>>(knn, cursor, csr);
    edge_kernel<<<1024, 256, 0, stream>>>(conv, knn, rowstart, csr, wp2, wp3, xh);
    sa_kernel  <<<512, 256, 0, stream>>>(conv, xh, swp1, swp2, swp3, scene_map);
    head1_kernel<<<16, 128, 0, stream>>>(conv, xh, scene_map, qidx, h1ws);
    head2_kernel<<<1, 256, 0, stream>>>(conv, h1ws, flag, (void*)d_out);
}

// Round 6
// 453.847 us; speedup vs baseline: 9.9016x; 1.3589x over previous
//
#include <hip/hip_runtime.h>

#define BB 4
#define NN 4096
#define KK 16

typedef unsigned short u16;
typedef unsigned int   u32;
typedef unsigned long long u64;

typedef __attribute__((ext_vector_type(8))) short bf16x8;
typedef __attribute__((ext_vector_type(4))) float f32x4;

__device__ __forceinline__ float b2f(u16 x){ return __uint_as_float(((u32)x) << 16); }
__device__ __forceinline__ u16 f2b(float f){
    u32 u = __float_as_uint(f);
    u32 r = (u + 0x7FFFu + ((u >> 16) & 1u)) >> 16;   // RNE
    return (u16)r;
}
__device__ __forceinline__ u32 fmap(float f){
    u32 u = __float_as_uint(f);
    return (u & 0x80000000u) ? ~u : (u | 0x80000000u);
}
__device__ __forceinline__ float funmap(u32 u){
    u32 v = (u & 0x80000000u) ? (u ^ 0x80000000u) : ~u;
    return __uint_as_float(v);
}

// ---------------- input normalization (runtime dtype detect: f32 vs bf16) ----
#define N_ARR 27
__device__ const int ASZ[N_ARR] = {
    49152, 384, 64, 64, 64, 8192, 128, 128, 128, 32768, 256,
    66304, 256, 256, 256, 131072, 512, 512, 512, 524288, 1024,
    655360, 512, 131072, 256, 4096, 16 };
__device__ const int AOFF[N_ARR] = {
    0, 49152, 49536, 49600, 49664, 49728, 57920, 58048, 58176, 58304, 91072,
    91328, 157632, 157888, 158144, 158400, 289472, 289984, 290496, 291008, 815296,
    816320, 1471680, 1472192, 1603264, 1603520, 1607616 };

struct Ptrs { const void* p[N_ARR]; };

#define O_POS 0
#define O_CW1 49152
#define O_CB1 49536
#define O_CG1 49600
#define O_CS1 49664
#define O_CW2 49728
#define O_CB2 57920
#define O_CG2 58048
#define O_CS2 58176
#define O_CW3 58304
#define O_CB3 91072
#define O_SW1 91328
#define O_SB1 157632
#define O_SG1 157888
#define O_SS1 158144
#define O_SW2 158400
#define O_SB2 289472
#define O_SG2 289984
#define O_SS2 290496
#define O_SW3 291008
#define O_SB3 815296
#define O_PW1 816320
#define O_PB1 1471680
#define O_PW2 1472192
#define O_PB2 1603264
#define O_PW3 1603520
#define O_PB3 1607616

__global__ void detect_kernel(const u16* __restrict__ pos_u16, u32* __restrict__ flag){
    __shared__ int cnt;
    if (threadIdx.x == 0) cnt = 0;
    __syncthreads();
    int c = 0;
    #pragma unroll
    for (int s = 0; s < 4; ++s){
        u16 u = pos_u16[2*(threadIdx.x*4 + s)];
        int e = (u >> 7) & 0xFF;
        c += (e >= 0x68 && e <= 0x82) ? 1 : 0;
    }
    atomicAdd(&cnt, c);
    __syncthreads();
    if (threadIdx.x == 0) *flag = (cnt >= 512) ? 1u : 0u;   // 1 = bf16 inputs
}

// Pack weight matrix (row-major KxN) from SOURCE (f32 or bf16) into MFMA B-frag order:
// dst[((ks*N + n)*4 + lg)*8 + i] = bf16(W[(ks*32 + lg*8 + i)*N + n])
__device__ __forceinline__ void pack_one_src(const void* __restrict__ src, bool isbf,
                                             u16* __restrict__ dst, int tot, int log2n,
                                             int g, int T){
    const int nmask = (1 << log2n) - 1;
    for (int id = g; id < tot; id += T){
        int i = id & 7, lg = (id >> 3) & 3;
        int rest = id >> 5;
        int n = rest & nmask;
        int ks = rest >> log2n;
        int si = (ks*32 + lg*8 + i) << log2n | n;
        dst[id] = isbf ? ((const u16*)src)[si] : f2b(((const float*)src)[si]);
    }
}

// convert all arrays to f32 + pack the 5 MFMA weight matrices (reads raw inputs)
__global__ __launch_bounds__(256) void prep_kernel(Ptrs pt, const u32* __restrict__ flagp,
        float* __restrict__ dst,
        u16* __restrict__ wp2, u16* __restrict__ wp3,
        u16* __restrict__ swp1, u16* __restrict__ swp2, u16* __restrict__ swp3){
    const bool isbf = (*flagp != 0);
    const int T = gridDim.x * 256;
    const int g = blockIdx.x * 256 + threadIdx.x;
    #pragma unroll
    for (int a = 0; a < N_ARR; ++a){
        const int sz = ASZ[a], off = AOFF[a];
        if (isbf){
            const u16* s = (const u16*)pt.p[a];
            for (int i = g; i < sz; i += T) dst[off + i] = b2f(s[i]);
        } else {
            const float* s = (const float*)pt.p[a];
            for (int i = g; i < sz; i += T) dst[off + i] = s[i];
        }
    }
    pack_one_src(pt.p[5],  isbf, wp2,    8192,  7, g, T);
    pack_one_src(pt.p[9],  isbf, wp3,   32768,  8, g, T);
    pack_one_src(pt.p[11], isbf, swp1,  65536,  8, g, T);   // first 256 K-rows of sw1
    pack_one_src(pt.p[15], isbf, swp2, 131072,  9, g, T);
    pack_one_src(pt.p[19], isbf, swp3, 524288, 10, g, T);
}

// ---------------------------------------------------------------- kNN (+ degree count)
__global__ __launch_bounds__(256) void knn_kernel(const float* __restrict__ conv,
                                                  int* __restrict__ knn_out,
                                                  u32* __restrict__ deg){
    __shared__ float sx[NN], sy[NN], sz[NN];
    const float* posf = conv + O_POS;
    const int b  = blockIdx.x >> 10;
    const int i0 = (blockIdx.x & 1023) << 2;
    const int tid = threadIdx.x;
    for (int t = tid; t < NN; t += 256){
        const float* p = posf + ((size_t)(b*NN + t))*3;
        sx[t] = p[0]; sy[t] = p[1]; sz[t] = p[2];
    }
    __syncthreads();
    const int lane = tid & 63;
    const int i = i0 + (tid >> 6);
    const float pix = sx[i], piy = sy[i], piz = sz[i];

    float d[KK]; int id[KK];
    #pragma unroll
    for (int t = 0; t < KK; ++t){
        int j = lane + (t << 6);
        float dx = pix - sx[j], dy = piy - sy[j], dz = piz - sz[j];
        d[t] = __fadd_rn(__fadd_rn(__fmul_rn(dx,dx), __fmul_rn(dy,dy)), __fmul_rn(dz,dz));
        id[t] = j;
    }
    float dmax = d[0]; int amax = 0;
    #pragma unroll
    for (int p = 1; p < KK; ++p){ bool c = d[p] > dmax; dmax = c ? d[p] : dmax; amax = c ? p : amax; }

    for (int t = KK; t < 64; ++t){
        int j = lane + (t << 6);
        float dx = pix - sx[j], dy = piy - sy[j], dz = piz - sz[j];
        float d2 = __fadd_rn(__fadd_rn(__fmul_rn(dx,dx), __fmul_rn(dy,dy)), __fmul_rn(dz,dz));
        if (d2 < dmax){
            #pragma unroll
            for (int p = 0; p < KK; ++p){ bool c = (p == amax); d[p] = c ? d2 : d[p]; id[p] = c ? j : id[p]; }
            dmax = d[0]; amax = 0;
            #pragma unroll
            for (int p = 1; p < KK; ++p){ bool c = d[p] > dmax; dmax = c ? d[p] : dmax; amax = c ? p : amax; }
        }
    }
    u64 key[KK];
    #pragma unroll
    for (int p = 0; p < KK; ++p) key[p] = (((u64)__float_as_uint(d[p])) << 32) | (u32)id[p];
    int* outp = knn_out + ((size_t)(b*NN + i))*KK;
    for (int r = 0; r < KK; ++r){
        u64 m = key[0];
        #pragma unroll
        for (int p = 1; p < KK; ++p) m = key[p] < m ? key[p] : m;
        #pragma unroll
        for (int off = 32; off > 0; off >>= 1){
            u64 o = __shfl_xor(m, off);
            m = o < m ? o : m;
        }
        if (lane == 0){
            int j = (int)(u32)(m & 0xFFFFFFFFu);
            outp[r] = j;
            atomicAdd(deg + (b << 12) + j, 1u);
        }
        #pragma unroll
        for (int p = 0; p < KK; ++p) if (key[p] == m) key[p] = ~0ull;
    }
}

// ---------------------------------------------------------------- CSR build
__global__ __launch_bounds__(1024) void scan_kernel(const u32* __restrict__ deg,
                                                    int* __restrict__ rowstart, u32* __restrict__ cursor){
    __shared__ int lsum[1024];
    const int tid = threadIdx.x;
    const int base = tid * 16;
    int loc[16]; int s = 0;
    #pragma unroll
    for (int q = 0; q < 16; ++q){ loc[q] = (int)deg[base+q]; s += loc[q]; }
    lsum[tid] = s;
    __syncthreads();
    int acc = s;
    for (int ofs = 1; ofs < 1024; ofs <<= 1){
        int t = (tid >= ofs) ? lsum[tid-ofs] : 0;
        __syncthreads();
        acc += t; lsum[tid] = acc;
        __syncthreads();
    }
    int excl = acc - s;
    #pragma unroll
    for (int q = 0; q < 16; ++q){
        rowstart[base+q] = excl; cursor[base+q] = (u32)excl; excl += loc[q];
    }
    if (tid == 1023) rowstart[16384] = excl;
}

__global__ __launch_bounds__(256) void fill_kernel(const int* __restrict__ knn,
                                                   u32* __restrict__ cursor, int* __restrict__ csr){
    int e = blockIdx.x*256 + threadIdx.x;
    int b = e >> 16;
    int t = (b << 12) + knn[e];
    u32 pos = atomicAdd(cursor + t, 1u);
    csr[pos] = e;
}

// ---------------------------------------------------------------- LDS fragment helpers
__device__ __forceinline__ bf16x8 ldfrag(const u16* h, int row, int kofs, int rowstride){
    u32 byte = (u32)((row*rowstride + kofs)*2) ^ (u32)((row & 7) << 4);
    return *(const bf16x8*)((const char*)h + byte);
}
__device__ __forceinline__ void st16(u16* h, int row, int col, int rowstride, float v){
    u32 byte = (u32)((row*rowstride + col)*2) ^ (u32)((row & 7) << 4);
    *(u16*)((char*)h + byte) = f2b(v);
}

// ---------------------------------------------------------------- edge MLP (MFMA) + segment max
// Streams B-fragments from L2 (no resident weight regs -> no spills).
// Segmented max done on the MFMA accumulator via LDS fmap/atomicMax.
__global__ __launch_bounds__(256, 2) void edge_kernel(
    const float* __restrict__ conv, const int* __restrict__ knn,
    const int* __restrict__ rowstart, const int* __restrict__ csr,
    const u16* __restrict__ wp2, const u16* __restrict__ wp3,
    u16* __restrict__ xh)
{
    __shared__ float in6[6][64];
    __shared__ int   lts[64];
    __shared__ int   rs_l[17];
    __shared__ float scw1[384];
    __shared__ float sc1[64], sh1[64];
    __shared__ __align__(16) u16 h1s[64*64];    // 8 KB swizzled [edge][ch]
    __shared__ __align__(16) u16 h2s[64*128];   // 16 KB swizzled
    __shared__ u32 lsx[16*256];                 // 16 KB fmap-max accumulator [target][ch]

    const float* posf = conv + O_POS;
    const float* cb1 = conv + O_CB1; const float* cg1 = conv + O_CG1; const float* cs1 = conv + O_CS1;

    const int tid = threadIdx.x;
    const int w   = tid >> 6;
    const int l   = tid & 63;
    const int t0  = blockIdx.x << 4;
    const int b   = t0 >> 12;

    if (tid < 64){ float g1 = cg1[tid]; sc1[tid]=g1; sh1[tid]=cb1[tid]*g1 + cs1[tid]; }
    if (tid < 17) rs_l[tid] = rowstart[t0 + tid];
    for (int u = tid; u < 384; u += 256) scw1[u] = conv[O_CW1 + u];
    #pragma unroll
    for (int q = 0; q < 16; ++q) lsx[q*256 + tid] = 0u;   // fmap identity (< any real value)

    const int lr = l & 15, lg = l >> 4;
    const int colb2 = w << 5;          // layer-2 cols [w*32, +32)
    const int colb3 = w << 6;          // layer-3 cols [w*64, +64)

    float sc2v[2], sh2v[2], bs3v[4];
    #pragma unroll
    for (int nt = 0; nt < 2; ++nt){
        int c = colb2 + nt*16 + lr;
        float g2 = conv[O_CG2 + c];
        sc2v[nt] = g2; sh2v[nt] = conv[O_CB2 + c]*g2 + conv[O_CS2 + c];
    }
    #pragma unroll
    for (int nt = 0; nt < 4; ++nt) bs3v[nt] = conv[O_CB3 + colb3 + nt*16 + lr];

    __syncthreads();
    const int segstart = rs_l[0], segend = rs_l[16];
    const int nchunk = (segend - segstart + 63) >> 6;

    int curl = -1;
    float run[4];
    #pragma unroll
    for (int nt = 0; nt < 4; ++nt) run[nt] = 0.f;

    for (int ch = 0; ch < nchunk; ++ch){
        __syncthreads();   // prev chunk's lts/in6/LDS fully consumed
        if (tid < 64){
            int gpos = segstart + (ch << 6) + tid;
            int lt = -1;
            float ax=0,ay=0,az=0,dx=0,dy=0,dz=0;
            if (gpos < segend){
                lt = 0;
                #pragma unroll
                for (int q = 1; q < 16; ++q) lt += (gpos >= rs_l[q]) ? 1 : 0;
                int e = csr[gpos];
                int i = (e >> 4) & (NN - 1);
                int j = knn[e];
                const float* pi = posf + ((size_t)(b*NN + i))*3;
                const float* pj = posf + ((size_t)(b*NN + j))*3;
                ax = pi[0]; ay = pi[1]; az = pi[2];
                dx = ax - pj[0]; dy = ay - pj[1]; dz = az - pj[2];
            }
            lts[tid] = lt;
            in6[0][tid]=ax; in6[1][tid]=ay; in6[2][tid]=az;
            in6[3][tid]=dx; in6[4][tid]=dy; in6[5][tid]=dz;
        }
        __syncthreads();

        { // layer 1 (VALU, K=6): thread -> edge tid&63, channels (tid>>6)*16..+15
            const int e = tid & 63, c0g = (tid >> 6) << 4;
            float a0=in6[0][e], a1=in6[1][e], a2=in6[2][e],
                  a3=in6[3][e], a4=in6[4][e], a5=in6[5][e];
            u32 pk[8];
            #pragma unroll
            for (int ci = 0; ci < 16; ++ci){
                int cc = c0g + ci;
                float acc = a0*scw1[cc]     + a1*scw1[64+cc]  + a2*scw1[128+cc]
                          + a3*scw1[192+cc] + a4*scw1[256+cc] + a5*scw1[320+cc];
                float v = fmaxf(acc*sc1[cc] + sh1[cc], 0.f);
                u32 h = (u32)f2b(v);
                if (ci & 1) pk[ci >> 1] |= h << 16; else pk[ci >> 1] = h;
            }
            u32 base = (u32)(e*128 + c0g*2);
            u32 swz  = (u32)((e & 7) << 4);
            *(uint4*)((char*)h1s + (base ^ swz))        = make_uint4(pk[0],pk[1],pk[2],pk[3]);
            *(uint4*)((char*)h1s + ((base + 16) ^ swz)) = make_uint4(pk[4],pk[5],pk[6],pk[7]);
        }
        __syncthreads();

        { // layer 2 (MFMA): M=64, N=128 (wave: 32 cols), K=64; B streamed
            f32x4 acc2[4][2];
            #pragma unroll
            for (int mt = 0; mt < 4; ++mt)
                #pragma unroll
                for (int nt = 0; nt < 2; ++nt) acc2[mt][nt] = (f32x4){0.f,0.f,0.f,0.f};
            #pragma unroll
            for (int ks = 0; ks < 2; ++ks){
                bf16x8 bf[2];
                #pragma unroll
                for (int nt = 0; nt < 2; ++nt)
                    bf[nt] = *(const bf16x8*)(wp2 + (((ks*128 + colb2 + nt*16 + lr) << 2) + lg)*8);
                #pragma unroll
                for (int mt = 0; mt < 4; ++mt){
                    bf16x8 a = ldfrag(h1s, mt*16 + lr, ks*32 + lg*8, 64);
                    #pragma unroll
                    for (int nt = 0; nt < 2; ++nt)
                        acc2[mt][nt] = __builtin_amdgcn_mfma_f32_16x16x32_bf16(a, bf[nt], acc2[mt][nt], 0, 0, 0);
                }
            }
            #pragma unroll
            for (int mt = 0; mt < 4; ++mt)
                #pragma unroll
                for (int nt = 0; nt < 2; ++nt)
                    #pragma unroll
                    for (int r = 0; r < 4; ++r){
                        int row = mt*16 + lg*4 + r;
                        float v = fmaxf(acc2[mt][nt][r]*sc2v[nt] + sh2v[nt], 0.f);
                        st16(h2s, row, colb2 + nt*16 + lr, 128, v);
                    }
        }
        __syncthreads();

        { // layer 3 (MFMA): M=64, N=256 (wave: 64 cols), K=128; B streamed;
          // segmented max flushed straight from the accumulator into lsx
            f32x4 acc3[4][4];
            #pragma unroll
            for (int mt = 0; mt < 4; ++mt)
                #pragma unroll
                for (int nt = 0; nt < 4; ++nt) acc3[mt][nt] = (f32x4){0.f,0.f,0.f,0.f};
            #pragma unroll
            for (int ks = 0; ks < 4; ++ks){
                bf16x8 bf[4];
                #pragma unroll
                for (int nt = 0; nt < 4; ++nt)
                    bf[nt] = *(const bf16x8*)(wp3 + (((ks*256 + colb3 + nt*16 + lr) << 2) + lg)*8);
                #pragma unroll
                for (int mt = 0; mt < 4; ++mt){
                    bf16x8 a = ldfrag(h2s, mt*16 + lr, ks*32 + lg*8, 128);
                    #pragma unroll
                    for (int nt = 0; nt < 4; ++nt)
                        acc3[mt][nt] = __builtin_amdgcn_mfma_f32_16x16x32_bf16(a, bf[nt], acc3[mt][nt], 0, 0, 0);
                }
            }
            // per-lane run-length segmented max (rows ascend per lane; labels sorted)
            #pragma unroll
            for (int mt = 0; mt < 4; ++mt)
                #pragma unroll
                for (int r = 0; r < 4; ++r){
                    int row = mt*16 + lg*4 + r;
                    int lt = lts[row];
                    if (lt != curl){
                        if (curl >= 0){
                            #pragma unroll
                            for (int nt = 0; nt < 4; ++nt)
                                atomicMax(&lsx[curl*256 + colb3 + nt*16 + lr], fmap(run[nt]));
                        }
                        curl = lt;
                        #pragma unroll
                        for (int nt = 0; nt < 4; ++nt) run[nt] = acc3[mt][nt][r] + bs3v[nt];
                    } else {
                        #pragma unroll
                        for (int nt = 0; nt < 4; ++nt) run[nt] = fmaxf(run[nt], acc3[mt][nt][r] + bs3v[nt]);
                    }
                }
        }
    }
    if (curl >= 0){
        #pragma unroll
        for (int nt = 0; nt < 4; ++nt)
            atomicMax(&lsx[curl*256 + colb3 + nt*16 + lr], fmap(run[nt]));
    }
    __syncthreads();
    #pragma unroll
    for (int q = 0; q < 16; ++q)
        xh[((size_t)(t0+q))*256 + tid] = f2b(funmap(lsx[q*256 + tid]));
}

// ---------------------------------------------------------------- GlobalSA MLP (MFMA) + scene max
__global__ __launch_bounds__(256, 2) void sa_kernel(
    const float* __restrict__ conv, const u16* __restrict__ xh,
    const u16* __restrict__ swp1, const u16* __restrict__ swp2, const u16* __restrict__ swp3,
    u32* __restrict__ scene_map)
{
    __shared__ __align__(16) u16 a0s[32*256];   // 16KB swizzled [pt][ch]
    __shared__ __align__(16) u16 h1s[32*256];   // 16KB
    __shared__ __align__(16) u16 h2s[32*512];   // 32KB
    __shared__ float spw[3][256];
    __shared__ float spx[32], spy[32], spz[32];

    const int tid = threadIdx.x;
    const int w   = tid >> 6;
    const int l   = tid & 63;
    const int lr  = l & 15, lg = l >> 4;
    const int b   = blockIdx.x >> 7;
    const int n0  = (blockIdx.x & 127) << 5;

    #pragma unroll
    for (int it = 0; it < 4; ++it){
        int slot = it*256 + tid;
        int row = slot >> 5, ch0 = (slot & 31) << 3;
        uint4 v = *(const uint4*)(xh + ((size_t)(b*NN + n0 + row))*256 + ch0);
        *(uint4*)((char*)a0s + ((u32)(row*512 + ch0*2) ^ (u32)((row & 7) << 4))) = v;
    }
    if (tid < 96){
        int p = tid & 31, d = tid >> 5;
        float v = conv[O_POS + ((size_t)(b*NN + n0 + p))*3 + d];
        if (d == 0) spx[p] = v; else if (d == 1) spy[p] = v; else spz[p] = v;
    }
    for (int u = tid; u < 768; u += 256)
        spw[u >> 8][u & 255] = conv[O_SW1 + (256 + (u >> 8))*256 + (u & 255)];
    __syncthreads();

    { // s1: 259 -> 256 ; wave cols [w*64, +64)
        const int c0 = w << 6;
        float sc1v[4], sh1v[4];
        #pragma unroll
        for (int nt = 0; nt < 4; ++nt){
            int cc = c0 + nt*16 + lr;
            float g = conv[O_SG1 + cc];
            sc1v[nt] = g; sh1v[nt] = conv[O_SB1 + cc]*g + conv[O_SS1 + cc];
        }
        f32x4 acc[2][4];
        #pragma unroll
        for (int mt = 0; mt < 2; ++mt)
            #pragma unroll
            for (int nt = 0; nt < 4; ++nt)
                #pragma unroll
                for (int r = 0; r < 4; ++r){
                    int row = mt*16 + lg*4 + r;
                    int cc  = c0 + nt*16 + lr;
                    acc[mt][nt][r] = spx[row]*spw[0][cc] + spy[row]*spw[1][cc] + spz[row]*spw[2][cc];
                }
        #pragma unroll
        for (int ks = 0; ks < 8; ++ks){
            bf16x8 bf[4];
            #pragma unroll
            for (int nt = 0; nt < 4; ++nt)
                bf[nt] = *(const bf16x8*)(swp1 + (((ks*256 + c0 + nt*16 + lr) << 2) + lg)*8);
            #pragma unroll
            for (int mt = 0; mt < 2; ++mt){
                bf16x8 a = ldfrag(a0s, mt*16 + lr, ks*32 + lg*8, 256);
                #pragma unroll
                for (int nt = 0; nt < 4; ++nt)
                    acc[mt][nt] = __builtin_amdgcn_mfma_f32_16x16x32_bf16(a, bf[nt], acc[mt][nt], 0, 0, 0);
            }
        }
        #pragma unroll
        for (int mt = 0; mt < 2; ++mt)
            #pragma unroll
            for (int nt = 0; nt < 4; ++nt)
                #pragma unroll
                for (int r = 0; r < 4; ++r){
                    int row = mt*16 + lg*4 + r;
                    float v = fmaxf(acc[mt][nt][r]*sc1v[nt] + sh1v[nt], 0.f);
                    st16(h1s, row, c0 + nt*16 + lr, 256, v);
                }
    }
    __syncthreads();

    { // s2: 256 -> 512 ; wave cols [w*128, +128)
        const int c0 = w << 7;
        float sc2v[8], sh2v[8];
        #pragma unroll
        for (int nt = 0; nt < 8; ++nt){
            int cc = c0 + nt*16 + lr;
            float g = conv[O_SG2 + cc];
            sc2v[nt] = g; sh2v[nt] = conv[O_SB2 + cc]*g + conv[O_SS2 + cc];
        }
        f32x4 acc[2][8];
        #pragma unroll
        for (int mt = 0; mt < 2; ++mt)
            #pragma unroll
            for (int nt = 0; nt < 8; ++nt) acc[mt][nt] = (f32x4){0.f,0.f,0.f,0.f};
        #pragma unroll
        for (int ks = 0; ks < 8; ++ks){
            bf16x8 bf[8];
            #pragma unroll
            for (int nt = 0; nt < 8; ++nt)
                bf[nt] = *(const bf16x8*)(swp2 + (((ks*512 + c0 + nt*16 + lr) << 2) + lg)*8);
            #pragma unroll
            for (int mt = 0; mt < 2; ++mt){
                bf16x8 a = ldfrag(h1s, mt*16 + lr, ks*32 + lg*8, 256);
                #pragma unroll
                for (int nt = 0; nt < 8; ++nt)
                    acc[mt][nt] = __builtin_amdgcn_mfma_f32_16x16x32_bf16(a, bf[nt], acc[mt][nt], 0, 0, 0);
            }
        }
        #pragma unroll
        for (int mt = 0; mt < 2; ++mt)
            #pragma unroll
            for (int nt = 0; nt < 8; ++nt)
                #pragma unroll
                for (int r = 0; r < 4; ++r){
                    int row = mt*16 + lg*4 + r;
                    float v = fmaxf(acc[mt][nt][r]*sc2v[nt] + sh2v[nt], 0.f);
                    st16(h2s, row, c0 + nt*16 + lr, 512, v);
                }
    }
    __syncthreads();

    #pragma unroll
    for (int half = 0; half < 2; ++half){
        const int c0 = (half << 9) + (w << 7);
        f32x4 acc[2][8];
        #pragma unroll
        for (int mt = 0; mt < 2; ++mt)
            #pragma unroll
            for (int nt = 0; nt < 8; ++nt) acc[mt][nt] = (f32x4){0.f,0.f,0.f,0.f};
        #pragma unroll
        for (int ks = 0; ks < 16; ++ks){
            bf16x8 bf[8];
            #pragma unroll
            for (int nt = 0; nt < 8; ++nt)
                bf[nt] = *(const bf16x8*)(swp3 + (((ks*1024 + c0 + nt*16 + lr) << 2) + lg)*8);
            #pragma unroll
            for (int mt = 0; mt < 2; ++mt){
                bf16x8 a = ldfrag(h2s, mt*16 + lr, ks*32 + lg*8, 512);
                #pragma unroll
                for (int nt = 0; nt < 8; ++nt)
                    acc[mt][nt] = __builtin_amdgcn_mfma_f32_16x16x32_bf16(a, bf[nt], acc[mt][nt], 0, 0, 0);
            }
        }
        #pragma unroll
        for (int nt = 0; nt < 8; ++nt){
            float v = acc[0][nt][0];
            #pragma unroll
            for (int mt = 0; mt < 2; ++mt)
                #pragma unroll
                for (int r = 0; r < 4; ++r) v = fmaxf(v, acc[mt][nt][r]);
            v = fmaxf(v, __shfl_xor(v, 16));
            v = fmaxf(v, __shfl_xor(v, 32));
            if (lg == 0){
                int cc = c0 + nt*16 + lr;
                atomicMax(scene_map + (b << 10) + cc, fmap(v + conv[O_SB3 + cc]));
            }
        }
    }
}

// ---------------------------------------------------------------- head
__global__ __launch_bounds__(128) void head1_kernel(
    const float* __restrict__ conv,
    const u16* __restrict__ xh, const u32* __restrict__ scene_map, const int* __restrict__ qidx,
    float* __restrict__ h1out)
{
    __shared__ float ef[1280];
    const float* pw1 = conv + O_PW1; const float* pb1 = conv + O_PB1;
    const int b  = blockIdx.x >> 2;
    const int c0 = (blockIdx.x & 3) << 7;
    const int tid = threadIdx.x;
    const int q = qidx[b];
    for (int u = tid; u < 1280; u += 128){
        float v;
        if (u < 256) v = b2f(xh[(((size_t)(b*NN + q)) << 8) + u]);
        else         v = funmap(scene_map[(b << 10) + (u - 256)]);
        ef[u] = v;
    }
    __syncthreads();
    const int c = c0 + tid;
    float acc = pb1[c];
    for (int r = 0; r < 1280; ++r) acc += ef[r] * pw1[r*512 + c];
    h1out[(b << 9) + c] = fmaxf(acc, 0.f);
}

__global__ __launch_bounds__(256) void head2_kernel(
    const float* __restrict__ conv, const float* __restrict__ h1in,
    const u32* __restrict__ flagp, void* __restrict__ outv)
{
    __shared__ float h1[4][512];
    __shared__ float h2[4][256];
    const float* pw2 = conv + O_PW2; const float* pb2 = conv + O_PB2;
    const float* pw3 = conv + O_PW3; const float* pb3 = conv + O_PB3;
    const int tid = threadIdx.x;
    for (int u = tid; u < 2048; u += 256) h1[u >> 9][u & 511] = h1in[u];
    __syncthreads();
    for (int o = tid; o < 1024; o += 256){
        int b = o >> 8, c = o & 255;
        float acc = pb2[c];
        for (int r = 0; r < 512; ++r) acc += h1[b][r] * pw2[r*256 + c];
        h2[b][c] = fmaxf(acc, 0.f);
    }
    __syncthreads();
    if (tid < 64){
        int b = tid >> 4, c = tid & 15;
        float acc = pb3[c];
        for (int r = 0; r < 256; ++r) acc += h2[b][r] * pw3[r*16 + c];
        if (*flagp) ((u16*)outv)[tid] = f2b(acc);
        else        ((float*)outv)[tid] = acc;
    }
}

// ---------------------------------------------------------------- launch
extern "C" void kernel_launch(void* const* d_in, const int* in_sizes, int n_in,
                              void* d_out, int out_size, void* d_ws, size_t ws_size,
                              hipStream_t stream){
    (void)in_sizes; (void)n_in; (void)out_size; (void)ws_size;
    const int* qidx = (const int*)d_in[1];

    char* ws = (char*)d_ws;
    u32*  flag      = (u32*)ws;                       // @0
    float* conv     = (float*)(ws + 1024);            // 6.43 MB f32
    u16*  wp2       = (u16*)(ws + 6432768);           // 16 KB  packed cw2
    u16*  wp3       = (u16*)(ws + 6449152);           // 64 KB  packed cw3
    u16*  swp1      = (u16*)(ws + 6514688);           // 128 KB packed sw1[0:256]
    u16*  swp2      = (u16*)(ws + 6645760);           // 256 KB packed sw2
    u16*  swp3      = (u16*)(ws + 6907904);           // 1 MB   packed sw3
    int*  knn       = (int*)(ws + 7956480);           // 1 MB
    u32*  deg       = (u32*)(ws + 9005056);           // 64 KB
    u32*  scene_map = (u32*)(ws + 9070592);           // 16 KB
    int*  rowstart  = (int*)(ws + 9086976);           // 64 KB + 4
    u32*  cursor    = (u32*)(ws + 9152576);           // 64 KB
    int*  csr       = (int*)(ws + 9218112);           // 1 MB
    u16*  xh        = (u16*)(ws + 10266688);          // 8 MB  [B*N, 256] bf16
    float* h1ws     = (float*)(ws + 18655296);        // 8 KB

    Ptrs pt;
    pt.p[0] = d_in[0];
    for (int k = 1; k < N_ARR; ++k) pt.p[k] = d_in[k + 1];

    hipMemsetAsync(ws + 9005056, 0, 81920, stream);   // deg + scene_map

    detect_kernel <<<1, 256, 0, stream>>>((const u16*)d_in[0], flag);
    prep_kernel   <<<512, 256, 0, stream>>>(pt, flag, conv, wp2, wp3, swp1, swp2, swp3);
    knn_kernel <<<4096, 256, 0, stream>>>(conv, knn, deg);
    scan_kernel<<<1, 1024, 0, stream>>>(deg, rowstart, cursor);
    fill_kernel<<<1024, 256, 0, stream>>>(knn, cursor, csr);
    edge_kernel<<<1024, 256, 0, stream>>>(conv, knn, rowstart, csr, wp2, wp3, xh);
    sa_kernel  <<<512, 256, 0, stream>>>(conv, xh, swp1, swp2, swp3, scene_map);
    head1_kernel<<<16, 128, 0, stream>>>(conv, xh, scene_map, qidx, h1ws);
    head2_kernel<<<1, 256, 0, stream>>>(conv, h1ws, flag, (void*)d_out);
}

// Round 7
// 395.620 us; speedup vs baseline: 11.3589x; 1.1472x over previous
//
#include <hip/hip_runtime.h>

#define BB 4
#define NN 4096
#define KK 16

typedef unsigned short u16;
typedef unsigned int   u32;
typedef unsigned long long u64;

typedef __attribute__((ext_vector_type(8))) short bf16x8;
typedef __attribute__((ext_vector_type(4))) float f32x4;

__device__ __forceinline__ float b2f(u16 x){ return __uint_as_float(((u32)x) << 16); }
__device__ __forceinline__ u16 f2b(float f){
    u32 u = __float_as_uint(f);
    u32 r = (u + 0x7FFFu + ((u >> 16) & 1u)) >> 16;   // RNE
    return (u16)r;
}
__device__ __forceinline__ u32 fmap(float f){
    u32 u = __float_as_uint(f);
    return (u & 0x80000000u) ? ~u : (u | 0x80000000u);
}
__device__ __forceinline__ float funmap(u32 u){
    u32 v = (u & 0x80000000u) ? (u ^ 0x80000000u) : ~u;
    return __uint_as_float(v);
}

// ---------------- input normalization (runtime dtype detect: f32 vs bf16) ----
#define N_ARR 27
__device__ const int ASZ[N_ARR] = {
    49152, 384, 64, 64, 64, 8192, 128, 128, 128, 32768, 256,
    66304, 256, 256, 256, 131072, 512, 512, 512, 524288, 1024,
    655360, 512, 131072, 256, 4096, 16 };
__device__ const int AOFF[N_ARR] = {
    0, 49152, 49536, 49600, 49664, 49728, 57920, 58048, 58176, 58304, 91072,
    91328, 157632, 157888, 158144, 158400, 289472, 289984, 290496, 291008, 815296,
    816320, 1471680, 1472192, 1603264, 1603520, 1607616 };

struct Ptrs { const void* p[N_ARR]; };

#define O_POS 0
#define O_CW1 49152
#define O_CB1 49536
#define O_CG1 49600
#define O_CS1 49664
#define O_CW2 49728
#define O_CB2 57920
#define O_CG2 58048
#define O_CS2 58176
#define O_CW3 58304
#define O_CB3 91072
#define O_SW1 91328
#define O_SB1 157632
#define O_SG1 157888
#define O_SS1 158144
#define O_SW2 158400
#define O_SB2 289472
#define O_SG2 289984
#define O_SS2 290496
#define O_SW3 291008
#define O_SB3 815296
#define O_PW1 816320
#define O_PB1 1471680
#define O_PW2 1472192
#define O_PB2 1603264
#define O_PW3 1603520
#define O_PB3 1607616

__global__ void detect_kernel(const u16* __restrict__ pos_u16, u32* __restrict__ flag){
    __shared__ int cnt;
    if (threadIdx.x == 0) cnt = 0;
    __syncthreads();
    int c = 0;
    #pragma unroll
    for (int s = 0; s < 4; ++s){
        u16 u = pos_u16[2*(threadIdx.x*4 + s)];
        int e = (u >> 7) & 0xFF;
        c += (e >= 0x68 && e <= 0x82) ? 1 : 0;
    }
    atomicAdd(&cnt, c);
    __syncthreads();
    if (threadIdx.x == 0) *flag = (cnt >= 512) ? 1u : 0u;   // 1 = bf16 inputs
}

// Pack weight matrix (row-major KxN) from SOURCE (f32 or bf16) into MFMA B-frag order:
// dst[((ks*N + n)*4 + lg)*8 + i] = bf16(W[(ks*32 + lg*8 + i)*N + n])
__device__ __forceinline__ void pack_one_src(const void* __restrict__ src, bool isbf,
                                             u16* __restrict__ dst, int tot, int log2n,
                                             int g, int T){
    const int nmask = (1 << log2n) - 1;
    for (int id = g; id < tot; id += T){
        int i = id & 7, lg = (id >> 3) & 3;
        int rest = id >> 5;
        int n = rest & nmask;
        int ks = rest >> log2n;
        int si = (ks*32 + lg*8 + i) << log2n | n;
        dst[id] = isbf ? ((const u16*)src)[si] : f2b(((const float*)src)[si]);
    }
}

// convert all arrays to f32 + pack the 5 MFMA weight matrices (reads raw inputs)
__global__ __launch_bounds__(256) void prep_kernel(Ptrs pt, const u32* __restrict__ flagp,
        float* __restrict__ dst,
        u16* __restrict__ wp2, u16* __restrict__ wp3,
        u16* __restrict__ swp1, u16* __restrict__ swp2, u16* __restrict__ swp3){
    const bool isbf = (*flagp != 0);
    const int T = gridDim.x * 256;
    const int g = blockIdx.x * 256 + threadIdx.x;
    #pragma unroll
    for (int a = 0; a < N_ARR; ++a){
        const int sz = ASZ[a], off = AOFF[a];
        if (isbf){
            const u16* s = (const u16*)pt.p[a];
            for (int i = g; i < sz; i += T) dst[off + i] = b2f(s[i]);
        } else {
            const float* s = (const float*)pt.p[a];
            for (int i = g; i < sz; i += T) dst[off + i] = s[i];
        }
    }
    pack_one_src(pt.p[5],  isbf, wp2,    8192,  7, g, T);
    pack_one_src(pt.p[9],  isbf, wp3,   32768,  8, g, T);
    pack_one_src(pt.p[11], isbf, swp1,  65536,  8, g, T);   // first 256 K-rows of sw1
    pack_one_src(pt.p[15], isbf, swp2, 131072,  9, g, T);
    pack_one_src(pt.p[19], isbf, swp3, 524288, 10, g, T);
}

// ---------------------------------------------------------------- kNN (+ degree count)
// Threshold-gated stream: fast path = dist + ballot; survivors appended to a
// per-wave LDS buffer; 16-way u64 extract (refine) only when buffer fills.
#define QCAP 192
__device__ __forceinline__ void refine16(u64* __restrict__ buf, int& cnt, float& tau, int lane){
    u64 loc[3];
    #pragma unroll
    for (int q = 0; q < 3; ++q){
        int p = lane + (q << 6);
        loc[q] = (p < cnt) ? buf[p] : ~0ull;
    }
    u64 m = ~0ull;
    #pragma unroll
    for (int r = 0; r < KK; ++r){
        m = loc[0];
        m = loc[1] < m ? loc[1] : m;
        m = loc[2] < m ? loc[2] : m;
        #pragma unroll
        for (int off = 32; off > 0; off >>= 1){
            u64 o = __shfl_xor(m, off);
            m = o < m ? o : m;
        }
        if (lane == r) buf[r] = m;
        #pragma unroll
        for (int q = 0; q < 3; ++q) if (loc[q] == m) loc[q] = ~0ull;
    }
    cnt = KK;
    tau = __uint_as_float((u32)(m >> 32));   // d2 of the 16th smallest (non-neg -> monotone)
}

__global__ __launch_bounds__(512) void knn_kernel(const float* __restrict__ conv,
                                                  int* __restrict__ knn_out,
                                                  u32* __restrict__ deg){
    __shared__ __align__(16) float sxy[NN*2];   // 32 KB
    __shared__ float szz[NN];                   // 16 KB
    __shared__ __align__(16) u64 kbuf[8*QCAP];  // 12 KB
    const float* posf = conv + O_POS;
    const int b  = blockIdx.x >> 9;             // 512 blocks per batch
    const int i0 = (blockIdx.x & 511) << 3;     // 8 queries per block
    const int tid = threadIdx.x;
    for (int t = tid; t < NN; t += 512){
        const float* p = posf + ((size_t)(b*NN + t))*3;
        sxy[2*t] = p[0]; sxy[2*t+1] = p[1]; szz[t] = p[2];
    }
    __syncthreads();
    const int lane = tid & 63;
    const int wq = tid >> 6;
    const int i = i0 + wq;
    const float pix = sxy[2*i], piy = sxy[2*i+1], piz = szz[i];
    u64* buf = kbuf + wq*QCAP;

    float tau = 3.0e38f;
    int cnt = 0;
    for (int t = 0; t < 64; ++t){
        int j = lane + (t << 6);
        float2 xy = *(const float2*)&sxy[2*j];
        float zz = szz[j];
        float dx = pix - xy.x, dy = piy - xy.y, dz = piz - zz;
        float d2 = __fadd_rn(__fadd_rn(__fmul_rn(dx,dx), __fmul_rn(dy,dy)), __fmul_rn(dz,dz));
        bool push = (d2 <= tau);
        u64 bal = __ballot(push);
        if (bal){
            int nins = __popcll(bal);
            if (cnt + nins > QCAP) refine16(buf, cnt, tau, lane);
            if (push){
                int ofs = __popcll(bal & ((1ull << lane) - 1ull));
                buf[cnt + ofs] = (((u64)__float_as_uint(d2)) << 32) | (u32)j;
            }
            cnt += nins;
        }
    }
    refine16(buf, cnt, tau, lane);
    if (lane < KK){
        u64 k = buf[lane];
        int j = (int)(u32)(k & 0xFFFFFFFFu);
        knn_out[((size_t)(b*NN + i))*KK + lane] = j;
        atomicAdd(deg + (b << 12) + j, 1u);
    }
}

// ---------------------------------------------------------------- CSR build
__global__ __launch_bounds__(1024) void scan_kernel(const u32* __restrict__ deg,
                                                    int* __restrict__ rowstart, u32* __restrict__ cursor){
    __shared__ int lsum[1024];
    const int tid = threadIdx.x;
    const int base = tid * 16;
    int loc[16]; int s = 0;
    #pragma unroll
    for (int q = 0; q < 16; ++q){ loc[q] = (int)deg[base+q]; s += loc[q]; }
    lsum[tid] = s;
    __syncthreads();
    int acc = s;
    for (int ofs = 1; ofs < 1024; ofs <<= 1){
        int t = (tid >= ofs) ? lsum[tid-ofs] : 0;
        __syncthreads();
        acc += t; lsum[tid] = acc;
        __syncthreads();
    }
    int excl = acc - s;
    #pragma unroll
    for (int q = 0; q < 16; ++q){
        rowstart[base+q] = excl; cursor[base+q] = (u32)excl; excl += loc[q];
    }
    if (tid == 1023) rowstart[16384] = excl;
}

__global__ __launch_bounds__(256) void fill_kernel(const int* __restrict__ knn,
                                                   u32* __restrict__ cursor, int* __restrict__ csr){
    int e = blockIdx.x*256 + threadIdx.x;
    int b = e >> 16;
    int t = (b << 12) + knn[e];
    u32 pos = atomicAdd(cursor + t, 1u);
    csr[pos] = e;
}

// ---------------------------------------------------------------- LDS fragment helpers
__device__ __forceinline__ bf16x8 ldfrag(const u16* h, int row, int kofs, int rowstride){
    u32 byte = (u32)((row*rowstride + kofs)*2) ^ (u32)((row & 7) << 4);
    return *(const bf16x8*)((const char*)h + byte);
}
__device__ __forceinline__ void st16(u16* h, int row, int col, int rowstride, float v){
    u32 byte = (u32)((row*rowstride + col)*2) ^ (u32)((row & 7) << 4);
    *(u16*)((char*)h + byte) = f2b(v);
}

// ---------------------------------------------------------------- edge MLP (MFMA) + segment max
__global__ __launch_bounds__(256, 2) void edge_kernel(
    const float* __restrict__ conv, const int* __restrict__ knn,
    const int* __restrict__ rowstart, const int* __restrict__ csr,
    const u16* __restrict__ wp2, const u16* __restrict__ wp3,
    u16* __restrict__ xh)
{
    __shared__ float in6[6][64];
    __shared__ int   lts[64];
    __shared__ int   rs_l[17];
    __shared__ float scw1[384];
    __shared__ float sc1[64], sh1[64];
    __shared__ __align__(16) u16 h1s[64*64];    // 8 KB swizzled [edge][ch]
    __shared__ __align__(16) u16 h2s[64*128];   // 16 KB swizzled
    __shared__ u32 lsx[16*256];                 // 16 KB fmap-max accumulator [target][ch]

    const float* posf = conv + O_POS;
    const float* cb1 = conv + O_CB1; const float* cg1 = conv + O_CG1; const float* cs1 = conv + O_CS1;

    const int tid = threadIdx.x;
    const int w   = tid >> 6;
    const int l   = tid & 63;
    const int t0  = blockIdx.x << 4;
    const int b   = t0 >> 12;

    if (tid < 64){ float g1 = cg1[tid]; sc1[tid]=g1; sh1[tid]=cb1[tid]*g1 + cs1[tid]; }
    if (tid < 17) rs_l[tid] = rowstart[t0 + tid];
    for (int u = tid; u < 384; u += 256) scw1[u] = conv[O_CW1 + u];
    #pragma unroll
    for (int q = 0; q < 16; ++q) lsx[q*256 + tid] = 0u;   // fmap identity (< any real value)

    const int lr = l & 15, lg = l >> 4;
    const int colb2 = w << 5;          // layer-2 cols [w*32, +32)
    const int colb3 = w << 6;          // layer-3 cols [w*64, +64)

    float sc2v[2], sh2v[2], bs3v[4];
    #pragma unroll
    for (int nt = 0; nt < 2; ++nt){
        int c = colb2 + nt*16 + lr;
        float g2 = conv[O_CG2 + c];
        sc2v[nt] = g2; sh2v[nt] = conv[O_CB2 + c]*g2 + conv[O_CS2 + c];
    }
    #pragma unroll
    for (int nt = 0; nt < 4; ++nt) bs3v[nt] = conv[O_CB3 + colb3 + nt*16 + lr];

    __syncthreads();
    const int segstart = rs_l[0], segend = rs_l[16];
    const int nchunk = (segend - segstart + 63) >> 6;

    int curl = -1;
    float run[4];
    #pragma unroll
    for (int nt = 0; nt < 4; ++nt) run[nt] = 0.f;

    for (int ch = 0; ch < nchunk; ++ch){
        __syncthreads();   // prev chunk's lts/in6/LDS fully consumed
        if (tid < 64){
            int gpos = segstart + (ch << 6) + tid;
            int lt = -1;
            float ax=0,ay=0,az=0,dx=0,dy=0,dz=0;
            if (gpos < segend){
                lt = 0;
                #pragma unroll
                for (int q = 1; q < 16; ++q) lt += (gpos >= rs_l[q]) ? 1 : 0;
                int e = csr[gpos];
                int i = (e >> 4) & (NN - 1);
                int j = knn[e];
                const float* pi = posf + ((size_t)(b*NN + i))*3;
                const float* pj = posf + ((size_t)(b*NN + j))*3;
                ax = pi[0]; ay = pi[1]; az = pi[2];
                dx = ax - pj[0]; dy = ay - pj[1]; dz = az - pj[2];
            }
            lts[tid] = lt;
            in6[0][tid]=ax; in6[1][tid]=ay; in6[2][tid]=az;
            in6[3][tid]=dx; in6[4][tid]=dy; in6[5][tid]=dz;
        }
        __syncthreads();

        { // layer 1 (VALU, K=6): thread -> edge tid&63, channels (tid>>6)*16..+15
            const int e = tid & 63, c0g = (tid >> 6) << 4;
            float a0=in6[0][e], a1=in6[1][e], a2=in6[2][e],
                  a3=in6[3][e], a4=in6[4][e], a5=in6[5][e];
            u32 pk[8];
            #pragma unroll
            for (int ci = 0; ci < 16; ++ci){
                int cc = c0g + ci;
                float acc = a0*scw1[cc]     + a1*scw1[64+cc]  + a2*scw1[128+cc]
                          + a3*scw1[192+cc] + a4*scw1[256+cc] + a5*scw1[320+cc];
                float v = fmaxf(acc*sc1[cc] + sh1[cc], 0.f);
                u32 h = (u32)f2b(v);
                if (ci & 1) pk[ci >> 1] |= h << 16; else pk[ci >> 1] = h;
            }
            u32 base = (u32)(e*128 + c0g*2);
            u32 swz  = (u32)((e & 7) << 4);
            *(uint4*)((char*)h1s + (base ^ swz))        = make_uint4(pk[0],pk[1],pk[2],pk[3]);
            *(uint4*)((char*)h1s + ((base + 16) ^ swz)) = make_uint4(pk[4],pk[5],pk[6],pk[7]);
        }
        __syncthreads();

        { // layer 2 (MFMA): M=64, N=128 (wave: 32 cols), K=64; B streamed
            f32x4 acc2[4][2];
            #pragma unroll
            for (int mt = 0; mt < 4; ++mt)
                #pragma unroll
                for (int nt = 0; nt < 2; ++nt) acc2[mt][nt] = (f32x4){0.f,0.f,0.f,0.f};
            #pragma unroll
            for (int ks = 0; ks < 2; ++ks){
                bf16x8 bf[2];
                #pragma unroll
                for (int nt = 0; nt < 2; ++nt)
                    bf[nt] = *(const bf16x8*)(wp2 + (((ks*128 + colb2 + nt*16 + lr) << 2) + lg)*8);
                #pragma unroll
                for (int mt = 0; mt < 4; ++mt){
                    bf16x8 a = ldfrag(h1s, mt*16 + lr, ks*32 + lg*8, 64);
                    #pragma unroll
                    for (int nt = 0; nt < 2; ++nt)
                        acc2[mt][nt] = __builtin_amdgcn_mfma_f32_16x16x32_bf16(a, bf[nt], acc2[mt][nt], 0, 0, 0);
                }
            }
            #pragma unroll
            for (int mt = 0; mt < 4; ++mt)
                #pragma unroll
                for (int nt = 0; nt < 2; ++nt)
                    #pragma unroll
                    for (int r = 0; r < 4; ++r){
                        int row = mt*16 + lg*4 + r;
                        float v = fmaxf(acc2[mt][nt][r]*sc2v[nt] + sh2v[nt], 0.f);
                        st16(h2s, row, colb2 + nt*16 + lr, 128, v);
                    }
        }
        __syncthreads();

        { // layer 3 (MFMA): M=64, N=256 (wave: 64 cols), K=128; B streamed;
          // segmented max flushed straight from the accumulator into lsx
            f32x4 acc3[4][4];
            #pragma unroll
            for (int mt = 0; mt < 4; ++mt)
                #pragma unroll
                for (int nt = 0; nt < 4; ++nt) acc3[mt][nt] = (f32x4){0.f,0.f,0.f,0.f};
            #pragma unroll
            for (int ks = 0; ks < 4; ++ks){
                bf16x8 bf[4];
                #pragma unroll
                for (int nt = 0; nt < 4; ++nt)
                    bf[nt] = *(const bf16x8*)(wp3 + (((ks*256 + colb3 + nt*16 + lr) << 2) + lg)*8);
                #pragma unroll
                for (int mt = 0; mt < 4; ++mt){
                    bf16x8 a = ldfrag(h2s, mt*16 + lr, ks*32 + lg*8, 128);
                    #pragma unroll
                    for (int nt = 0; nt < 4; ++nt)
                        acc3[mt][nt] = __builtin_amdgcn_mfma_f32_16x16x32_bf16(a, bf[nt], acc3[mt][nt], 0, 0, 0);
                }
            }
            // per-lane run-length segmented max (rows ascend per lane; labels sorted)
            #pragma unroll
            for (int mt = 0; mt < 4; ++mt)
                #pragma unroll
                for (int r = 0; r < 4; ++r){
                    int row = mt*16 + lg*4 + r;
                    int lt = lts[row];
                    if (lt != curl){
                        if (curl >= 0){
                            #pragma unroll
                            for (int nt = 0; nt < 4; ++nt)
                                atomicMax(&lsx[curl*256 + colb3 + nt*16 + lr], fmap(run[nt]));
                        }
                        curl = lt;
                        #pragma unroll
                        for (int nt = 0; nt < 4; ++nt) run[nt] = acc3[mt][nt][r] + bs3v[nt];
                    } else {
                        #pragma unroll
                        for (int nt = 0; nt < 4; ++nt) run[nt] = fmaxf(run[nt], acc3[mt][nt][r] + bs3v[nt]);
                    }
                }
        }
    }
    if (curl >= 0){
        #pragma unroll
        for (int nt = 0; nt < 4; ++nt)
            atomicMax(&lsx[curl*256 + colb3 + nt*16 + lr], fmap(run[nt]));
    }
    __syncthreads();
    #pragma unroll
    for (int q = 0; q < 16; ++q)
        xh[((size_t)(t0+q))*256 + tid] = f2b(funmap(lsx[q*256 + tid]));
}

// ---------------------------------------------------------------- GlobalSA MLP (MFMA) + scene max
__global__ __launch_bounds__(256, 2) void sa_kernel(
    const float* __restrict__ conv, const u16* __restrict__ xh,
    const u16* __restrict__ swp1, const u16* __restrict__ swp2, const u16* __restrict__ swp3,
    u32* __restrict__ scene_map)
{
    __shared__ __align__(16) u16 a0s[32*256];   // 16KB swizzled [pt][ch]
    __shared__ __align__(16) u16 h1s[32*256];   // 16KB
    __shared__ __align__(16) u16 h2s[32*512];   // 32KB
    __shared__ float spw[3][256];
    __shared__ float spx[32], spy[32], spz[32];

    const int tid = threadIdx.x;
    const int w   = tid >> 6;
    const int l   = tid & 63;
    const int lr  = l & 15, lg = l >> 4;
    const int b   = blockIdx.x >> 7;
    const int n0  = (blockIdx.x & 127) << 5;

    #pragma unroll
    for (int it = 0; it < 4; ++it){
        int slot = it*256 + tid;
        int row = slot >> 5, ch0 = (slot & 31) << 3;
        uint4 v = *(const uint4*)(xh + ((size_t)(b*NN + n0 + row))*256 + ch0);
        *(uint4*)((char*)a0s + ((u32)(row*512 + ch0*2) ^ (u32)((row & 7) << 4))) = v;
    }
    if (tid < 96){
        int p = tid & 31, d = tid >> 5;
        float v = conv[O_POS + ((size_t)(b*NN + n0 + p))*3 + d];
        if (d == 0) spx[p] = v; else if (d == 1) spy[p] = v; else spz[p] = v;
    }
    for (int u = tid; u < 768; u += 256)
        spw[u >> 8][u & 255] = conv[O_SW1 + (256 + (u >> 8))*256 + (u & 255)];
    __syncthreads();

    { // s1: 259 -> 256 ; wave cols [w*64, +64)
        const int c0 = w << 6;
        float sc1v[4], sh1v[4];
        #pragma unroll
        for (int nt = 0; nt < 4; ++nt){
            int cc = c0 + nt*16 + lr;
            float g = conv[O_SG1 + cc];
            sc1v[nt] = g; sh1v[nt] = conv[O_SB1 + cc]*g + conv[O_SS1 + cc];
        }
        f32x4 acc[2][4];
        #pragma unroll
        for (int mt = 0; mt < 2; ++mt)
            #pragma unroll
            for (int nt = 0; nt < 4; ++nt)
                #pragma unroll
                for (int r = 0; r < 4; ++r){
                    int row = mt*16 + lg*4 + r;
                    int cc  = c0 + nt*16 + lr;
                    acc[mt][nt][r] = spx[row]*spw[0][cc] + spy[row]*spw[1][cc] + spz[row]*spw[2][cc];
                }
        #pragma unroll
        for (int ks = 0; ks < 8; ++ks){
            bf16x8 bf[4];
            #pragma unroll
            for (int nt = 0; nt < 4; ++nt)
                bf[nt] = *(const bf16x8*)(swp1 + (((ks*256 + c0 + nt*16 + lr) << 2) + lg)*8);
            #pragma unroll
            for (int mt = 0; mt < 2; ++mt){
                bf16x8 a = ldfrag(a0s, mt*16 + lr, ks*32 + lg*8, 256);
                #pragma unroll
                for (int nt = 0; nt < 4; ++nt)
                    acc[mt][nt] = __builtin_amdgcn_mfma_f32_16x16x32_bf16(a, bf[nt], acc[mt][nt], 0, 0, 0);
            }
        }
        #pragma unroll
        for (int mt = 0; mt < 2; ++mt)
            #pragma unroll
            for (int nt = 0; nt < 4; ++nt)
                #pragma unroll
                for (int r = 0; r < 4; ++r){
                    int row = mt*16 + lg*4 + r;
                    float v = fmaxf(acc[mt][nt][r]*sc1v[nt] + sh1v[nt], 0.f);
                    st16(h1s, row, c0 + nt*16 + lr, 256, v);
                }
    }
    __syncthreads();

    { // s2: 256 -> 512 ; wave cols [w*128, +128)
        const int c0 = w << 7;
        float sc2v[8], sh2v[8];
        #pragma unroll
        for (int nt = 0; nt < 8; ++nt){
            int cc = c0 + nt*16 + lr;
            float g = conv[O_SG2 + cc];
            sc2v[nt] = g; sh2v[nt] = conv[O_SB2 + cc]*g + conv[O_SS2 + cc];
        }
        f32x4 acc[2][8];
        #pragma unroll
        for (int mt = 0; mt < 2; ++mt)
            #pragma unroll
            for (int nt = 0; nt < 8; ++nt) acc[mt][nt] = (f32x4){0.f,0.f,0.f,0.f};
        #pragma unroll
        for (int ks = 0; ks < 8; ++ks){
            bf16x8 bf[8];
            #pragma unroll
            for (int nt = 0; nt < 8; ++nt)
                bf[nt] = *(const bf16x8*)(swp2 + (((ks*512 + c0 + nt*16 + lr) << 2) + lg)*8);
            #pragma unroll
            for (int mt = 0; mt < 2; ++mt){
                bf16x8 a = ldfrag(h1s, mt*16 + lr, ks*32 + lg*8, 256);
                #pragma unroll
                for (int nt = 0; nt < 8; ++nt)
                    acc[mt][nt] = __builtin_amdgcn_mfma_f32_16x16x32_bf16(a, bf[nt], acc[mt][nt], 0, 0, 0);
            }
        }
        #pragma unroll
        for (int mt = 0; mt < 2; ++mt)
            #pragma unroll
            for (int nt = 0; nt < 8; ++nt)
                #pragma unroll
                for (int r = 0; r < 4; ++r){
                    int row = mt*16 + lg*4 + r;
                    float v = fmaxf(acc[mt][nt][r]*sc2v[nt] + sh2v[nt], 0.f);
                    st16(h2s, row, c0 + nt*16 + lr, 512, v);
                }
    }
    __syncthreads();

    #pragma unroll
    for (int half = 0; half < 2; ++half){
        const int c0 = (half << 9) + (w << 7);
        f32x4 acc[2][8];
        #pragma unroll
        for (int mt = 0; mt < 2; ++mt)
            #pragma unroll
            for (int nt = 0; nt < 8; ++nt) acc[mt][nt] = (f32x4){0.f,0.f,0.f,0.f};
        #pragma unroll
        for (int ks = 0; ks < 16; ++ks){
            bf16x8 bf[8];
            #pragma unroll
            for (int nt = 0; nt < 8; ++nt)
                bf[nt] = *(const bf16x8*)(swp3 + (((ks*1024 + c0 + nt*16 + lr) << 2) + lg)*8);
            #pragma unroll
            for (int mt = 0; mt < 2; ++mt){
                bf16x8 a = ldfrag(h2s, mt*16 + lr, ks*32 + lg*8, 512);
                #pragma unroll
                for (int nt = 0; nt < 8; ++nt)
                    acc[mt][nt] = __builtin_amdgcn_mfma_f32_16x16x32_bf16(a, bf[nt], acc[mt][nt], 0, 0, 0);
            }
        }
        #pragma unroll
        for (int nt = 0; nt < 8; ++nt){
            float v = acc[0][nt][0];
            #pragma unroll
            for (int mt = 0; mt < 2; ++mt)
                #pragma unroll
                for (int r = 0; r < 4; ++r) v = fmaxf(v, acc[mt][nt][r]);
            v = fmaxf(v, __shfl_xor(v, 16));
            v = fmaxf(v, __shfl_xor(v, 32));
            if (lg == 0){
                int cc = c0 + nt*16 + lr;
                atomicMax(scene_map + (b << 10) + cc, fmap(v + conv[O_SB3 + cc]));
            }
        }
    }
}

// ---------------------------------------------------------------- head
__global__ __launch_bounds__(128) void head1_kernel(
    const float* __restrict__ conv,
    const u16* __restrict__ xh, const u32* __restrict__ scene_map, const int* __restrict__ qidx,
    float* __restrict__ h1out)
{
    __shared__ float ef[1280];
    const float* pw1 = conv + O_PW1; const float* pb1 = conv + O_PB1;
    const int b  = blockIdx.x >> 2;
    const int c0 = (blockIdx.x & 3) << 7;
    const int tid = threadIdx.x;
    const int q = qidx[b];
    for (int u = tid; u < 1280; u += 128){
        float v;
        if (u < 256) v = b2f(xh[(((size_t)(b*NN + q)) << 8) + u]);
        else         v = funmap(scene_map[(b << 10) + (u - 256)]);
        ef[u] = v;
    }
    __syncthreads();
    const int c = c0 + tid;
    float acc = pb1[c];
    for (int r = 0; r < 1280; ++r) acc += ef[r] * pw1[r*512 + c];
    h1out[(b << 9) + c] = fmaxf(acc, 0.f);
}

__global__ __launch_bounds__(256) void head2_kernel(
    const float* __restrict__ conv, const float* __restrict__ h1in,
    const u32* __restrict__ flagp, void* __restrict__ outv)
{
    __shared__ float h1[4][512];
    __shared__ float h2[4][256];
    const float* pw2 = conv + O_PW2; const float* pb2 = conv + O_PB2;
    const float* pw3 = conv + O_PW3; const float* pb3 = conv + O_PB3;
    const int tid = threadIdx.x;
    for (int u = tid; u < 2048; u += 256) h1[u >> 9][u & 511] = h1in[u];
    __syncthreads();
    for (int o = tid; o < 1024; o += 256){
        int b = o >> 8, c = o & 255;
        float acc = pb2[c];
        for (int r = 0; r < 512; ++r) acc += h1[b][r] * pw2[r*256 + c];
        h2[b][c] = fmaxf(acc, 0.f);
    }
    __syncthreads();
    if (tid < 64){
        int b = tid >> 4, c = tid & 15;
        float acc = pb3[c];
        for (int r = 0; r < 256; ++r) acc += h2[b][r] * pw3[r*16 + c];
        if (*flagp) ((u16*)outv)[tid] = f2b(acc);
        else        ((float*)outv)[tid] = acc;
    }
}

// ---------------------------------------------------------------- launch
extern "C" void kernel_launch(void* const* d_in, const int* in_sizes, int n_in,
                              void* d_out, int out_size, void* d_ws, size_t ws_size,
                              hipStream_t stream){
    (void)in_sizes; (void)n_in; (void)out_size; (void)ws_size;
    const int* qidx = (const int*)d_in[1];

    char* ws = (char*)d_ws;
    u32*  flag      = (u32*)ws;                       // @0
    float* conv     = (float*)(ws + 1024);            // 6.43 MB f32
    u16*  wp2       = (u16*)(ws + 6432768);           // 16 KB  packed cw2
    u16*  wp3       = (u16*)(ws + 6449152);           // 64 KB  packed cw3
    u16*  swp1      = (u16*)(ws + 6514688);           // 128 KB packed sw1[0:256]
    u16*  swp2      = (u16*)(ws + 6645760);           // 256 KB packed sw2
    u16*  swp3      = (u16*)(ws + 6907904);           // 1 MB   packed sw3
    int*  knn       = (int*)(ws + 7956480);           // 1 MB
    u32*  deg       = (u32*)(ws + 9005056);           // 64 KB
    u32*  scene_map = (u32*)(ws + 9070592);           // 16 KB
    int*  rowstart  = (int*)(ws + 9086976);           // 64 KB + 4
    u32*  cursor    = (u32*)(ws + 9152576);           // 64 KB
    int*  csr       = (int*)(ws + 9218112);           // 1 MB
    u16*  xh        = (u16*)(ws + 10266688);          // 8 MB  [B*N, 256] bf16
    float* h1ws     = (float*)(ws + 18655296);        // 8 KB

    Ptrs pt;
    pt.p[0] = d_in[0];
    for (int k = 1; k < N_ARR; ++k) pt.p[k] = d_in[k + 1];

    hipMemsetAsync(ws + 9005056, 0, 81920, stream);   // deg + scene_map

    detect_kernel <<<1, 256, 0, stream>>>((const u16*)d_in[0], flag);
    prep_kernel   <<<512, 256, 0, stream>>>(pt, flag, conv, wp2, wp3, swp1, swp2, swp3);
    knn_kernel <<<2048, 512, 0, stream>>>(conv, knn, deg);
    scan_kernel<<<1, 1024, 0, stream>>>(deg, rowstart, cursor);
    fill_kernel<<<1024, 256, 0, stream>>>(knn, cursor, csr);
    edge_kernel<<<1024, 256, 0, stream>>>(conv, knn, rowstart, csr, wp2, wp3, xh);
    sa_kernel  <<<512, 256, 0, stream>>>(conv, xh, swp1, swp2, swp3, scene_map);
    head1_kernel<<<16, 128, 0, stream>>>(conv, xh, scene_map, qidx, h1ws);
    head2_kernel<<<1, 256, 0, stream>>>(conv, h1ws, flag, (void*)d_out);
}